// Round 6
// baseline (519.243 us; speedup 1.0000x reference)
//
#include <hip/hip_runtime.h>
#include <math.h>

#define H 1024
#define W 1024
#define HW (H * W)

typedef _Float16 half8 __attribute__((ext_vector_type(8)));
typedef _Float16 half4 __attribute__((ext_vector_type(4)));
typedef float f32x4 __attribute__((ext_vector_type(4)));
typedef unsigned uint4v __attribute__((ext_vector_type(4)));

__device__ __forceinline__ float fast_sqrtf(float x) { return __builtin_amdgcn_sqrtf(x); }
__device__ __forceinline__ float fast_expf(float x) { return __builtin_amdgcn_exp2f(x * 1.44269504088896340736f); }

union U16 { unsigned short u; _Float16 f; };

__device__ __forceinline__ unsigned pack_hl(float v) {
    _Float16 h = (_Float16)v;
    _Float16 l = (_Float16)(v - (float)h);
    U16 a, b;
    a.f = h; b.f = l;
    return (unsigned)a.u | ((unsigned)b.u << 16);
}

// unpack 8 packed u32 (f16h | f16l<<16) into the h-plane / l-plane half8 via v_perm_b32
__device__ __forceinline__ half8 unpack_lo8(const unsigned* u) {
    uint4v a;
    a.x = __builtin_amdgcn_perm(u[1], u[0], 0x05040100);
    a.y = __builtin_amdgcn_perm(u[3], u[2], 0x05040100);
    a.z = __builtin_amdgcn_perm(u[5], u[4], 0x05040100);
    a.w = __builtin_amdgcn_perm(u[7], u[6], 0x05040100);
    return __builtin_bit_cast(half8, a);
}
__device__ __forceinline__ half8 unpack_hi8(const unsigned* u) {
    uint4v a;
    a.x = __builtin_amdgcn_perm(u[1], u[0], 0x07060302);
    a.y = __builtin_amdgcn_perm(u[3], u[2], 0x07060302);
    a.z = __builtin_amdgcn_perm(u[5], u[4], 0x07060302);
    a.w = __builtin_amdgcn_perm(u[7], u[6], 0x07060302);
    return __builtin_bit_cast(half8, a);
}
__device__ __forceinline__ half8 unpack_lo4(const unsigned* u) {
    uint4v a;
    a.x = __builtin_amdgcn_perm(u[1], u[0], 0x05040100);
    a.y = __builtin_amdgcn_perm(u[3], u[2], 0x05040100);
    a.z = 0; a.w = 0;
    return __builtin_bit_cast(half8, a);
}
__device__ __forceinline__ half8 unpack_hi4(const unsigned* u) {
    uint4v a;
    a.x = __builtin_amdgcn_perm(u[1], u[0], 0x07060302);
    a.y = __builtin_amdgcn_perm(u[3], u[2], 0x07060302);
    a.z = 0; a.w = 0;
    return __builtin_bit_cast(half8, a);
}

// ---------------- stats pass 1: partial sum/sumsq per (b,c) chunk ----------------
__global__ __launch_bounds__(256) void stats_partial(const float* __restrict__ x,
                                                     double* __restrict__ part) {
    int blk = blockIdx.x;
    int bc = blk >> 5;
    int j = blk & 31;
    const float* p = x + (size_t)bc * HW + (size_t)j * (HW / 32);
    int tid = threadIdx.x;
    double s = 0.0, q = 0.0;
    const float4* p4 = (const float4*)p;
    for (int i = tid; i < (HW / 32) / 4; i += 256) {
        float4 v = p4[i];
        s += (double)v.x + (double)v.y + (double)v.z + (double)v.w;
        q += (double)v.x * v.x + (double)v.y * v.y + (double)v.z * v.z + (double)v.w * v.w;
    }
    __shared__ double ls[256], lq[256];
    ls[tid] = s;
    lq[tid] = q;
    __syncthreads();
    for (int ofs = 128; ofs > 0; ofs >>= 1) {
        if (tid < ofs) { ls[tid] += ls[tid + ofs]; lq[tid] += lq[tid + ofs]; }
        __syncthreads();
    }
    if (tid == 0) {
        part[blk * 2] = ls[0];
        part[blk * 2 + 1] = lq[0];
    }
}

// ---------------- stats pass 2 + weight prep ----------------
__global__ __launch_bounds__(256) void stats_final_prep(const double* __restrict__ part,
                                                        const float* __restrict__ chw,
                                                        const float* __restrict__ w1,
                                                        const float* __restrict__ w2,
                                                        const float* __restrict__ w3,
                                                        float* __restrict__ stats,
                                                        _Float16* __restrict__ w1a,
                                                        _Float16* __restrict__ w3f,
                                                        _Float16* __restrict__ w2bh,
                                                        _Float16* __restrict__ w2bl) {
    int tid = threadIdx.x;
    __shared__ float cw[4];
    if (tid == 0) {
        float m = fmaxf(fmaxf(chw[0], chw[1]), fmaxf(chw[2], chw[3]));
        float e0 = expf(chw[0] - m), e1 = expf(chw[1] - m);
        float e2 = expf(chw[2] - m), e3 = expf(chw[3] - m);
        float s = e0 + e1 + e2 + e3;
        cw[0] = e0 / s; cw[1] = e1 / s; cw[2] = e2 / s; cw[3] = e3 / s;
    }
    __syncthreads();
    if (tid < 16) {
        double s = 0.0, q = 0.0;
        for (int j = 0; j < 32; j++) {
            s += part[(tid * 32 + j) * 2];
            q += part[(tid * 32 + j) * 2 + 1];
        }
        double n = (double)HW;
        double var = (q - s * s / n) / (n - 1.0);
        if (var < 0) var = 0;
        float gs = (float)sqrt(var);
        int c = tid & 3;
        float gf = fminf(fmaxf(gs * 5.0f, 0.5f), 2.0f);
        float cf = fminf(fmaxf(gs * cw[c] * 2.0f, 0.8f), 1.2f);
        stats[tid * 2] = 0.05f * gf * cf;
        stats[tid * 2 + 1] = 0.20f * gf * cf;
    }
    for (int i = tid; i < 512; i += 256) {                 // conv1 A-frags
        int s = i >> 6, l = i & 63;
        int c = s >> 2, h = (s >> 1) & 1, hl = s & 1;
        int m = l & 15, cg = l >> 4;
        int co = h * 16 + m;
#pragma unroll
        for (int j = 0; j < 8; j++) {
            int k = c * 32 + cg * 8 + j;
            float v = 0.f;
            if (k < 36) {
                int t = k >> 2, ci = k & 3;
                v = w1[(co * 4 + ci) * 9 + t];
            }
            _Float16 hh = (_Float16)v;
            w1a[i * 8 + j] = hl ? (_Float16)(v - (float)hh) : hh;
        }
    }
    for (int idx = tid; idx < 576; idx += 256) {           // conv2 B-frags
        int t = idx >> 6, l = idx & 63;
        int co = l & 15, cg = l >> 4;
#pragma unroll
        for (int j = 0; j < 8; j++) {
            int ci = cg * 8 + j;
            float v = w2[(co * 32 + ci) * 9 + t];
            _Float16 hh = (_Float16)v;
            w2bh[idx * 8 + j] = hh;
            w2bl[idx * 8 + j] = (_Float16)(v - (float)hh);
        }
    }
    for (int idx = tid; idx < 768; idx += 256) {           // conv3 B-frags (12 sets x 64 lanes)
        int t = idx >> 6, l = idx & 63;
        int ky = t >> 2, grp = (t >> 1) & 1, hl = t & 1;
        int co = l & 15, bq = l >> 4;
#pragma unroll
        for (int j = 0; j < 8; j++) {
            int k = bq * 8 + j;
            float v = 0.f;
            if (co < 8) {
                if (grp == 0) {
                    int kxp = k >> 4, ci = k & 15;
                    v = w3[((co * 16 + ci) * 3 + ky) * 3 + kxp];
                } else if (k < 16) {
                    v = w3[((co * 16 + k) * 3 + ky) * 3 + 2];
                }
            }
            _Float16 hh = (_Float16)v;
            w3f[idx * 8 + j] = hl ? (_Float16)(v - (float)hh) : hh;
        }
    }
}

// ---------------- fused conv1+conv2, both via MFMA ----------------
// v6: f2n stored h-only (16 f16/px = 32B) -- tolerance probe; epilogue lighter.
__global__ __launch_bounds__(256, 3) void conv12_mfma(const float* __restrict__ x,
                                                      const _Float16* __restrict__ w1a,
                                                      const float* __restrict__ b1,
                                                      const _Float16* __restrict__ wbh,
                                                      const _Float16* __restrict__ wbl,
                                                      const float* __restrict__ b2,
                                                      _Float16* __restrict__ f2n) {
    __shared__ __align__(16) char smem[50432];
    char* f1t = smem;                                  // 10*34*128 = 43520 B (swizzled)
    unsigned* xhl = (unsigned*)(smem + 43520);         // [4][12][36] u32 (f16h | f16l<<16)
    int tid = threadIdx.x;
    int lane = tid & 63;
    int wid = tid >> 6;
    int bx = blockIdx.x * 32, by = blockIdx.y * 8;
    int n = lane & 15, cg = lane >> 4;
    int m = lane & 15, b = lane >> 4;

    // phase 1: stage x halo (rows by-2..by+9, cols bx-2..bx+33) as packed f16 h/l.
    {
        int idx = tid;
        int r = tid / 36, c = tid - r * 36, ci = 0;
#pragma unroll
        for (int it = 0; it < 7; ++it) {
            if (idx < 1728) {
                int gy = by + r - 2, gx = bx + c - 2;
                float v = 0.f;
                if ((unsigned)gy < H && (unsigned)gx < W) v = x[ci * HW + gy * W + gx];
                xhl[idx] = pack_hl(v);
            }
            idx += 256;
            c += 4; if (c >= 36) { c -= 36; r += 1; }
            r += 7; if (r >= 12) { r -= 12; ci += 1; }
        }
    }

    half8 Wf[8];
#pragma unroll
    for (int s = 0; s < 8; s++)
        Wf[s] = *(const half8*)(w1a + (s * 64 + lane) * 8);
    float bias1[8];
#pragma unroll
    for (int h = 0; h < 2; h++)
#pragma unroll
        for (int j = 0; j < 4; j++)
            bias1[h * 4 + j] = b1[h * 16 + cg * 4 + j];
    // conv2 weights hoisted: independent global loads, latency hides under conv1
    half8 Bh[9], Bl[9];
#pragma unroll
    for (int t = 0; t < 9; t++) {
        Bh[t] = *(const half8*)(wbh + (t * 64 + lane) * 8);
        Bl[t] = *(const half8*)(wbl + (t * 64 + lane) * 8);
    }
    f32x4 binit;
#pragma unroll
    for (int j = 0; j < 4; j++) binit[j] = b2[b * 4 + j];

    int t0 = 2 * cg, t1 = 2 * cg + 1;
    int dy0 = (t0 * 11) >> 5, dx0 = t0 - 3 * dy0;
    int dy1 = (t1 * 11) >> 5, dx1 = t1 - 3 * dy1;
    int off0 = dy0 * 36 + dx0, off1 = dy1 * 36 + dx1;
    __syncthreads();

    // phase 2: conv1 via MFMA; 22 tiles of 16 px cover the 340-px halo
#pragma unroll 1
    for (int tt = wid; tt < 22; tt += 4) {
        int p = tt * 16 + n;
        bool valid = p < 340;
        int pc = valid ? p : 339;
        int ry = pc / 34, cx = pc - ry * 34;
        int gy = by + ry - 1, gx = bx + cx - 1;
        bool ok = ((unsigned)gy < H) && ((unsigned)gx < W);
        int base = ry * 36 + cx;
        unsigned u0[8];
#pragma unroll
        for (int j = 0; j < 8; j++)
            u0[j] = xhl[(j & 3) * 432 + base + ((j < 4) ? off0 : off1)];
        half8 Xh0 = unpack_lo8(u0);
        half8 Xl0 = unpack_hi8(u0);
        half8 Xh1 = {0, 0, 0, 0, 0, 0, 0, 0}, Xl1 = {0, 0, 0, 0, 0, 0, 0, 0};
        if (cg == 0) {
            unsigned u1[4];
#pragma unroll
            for (int j = 0; j < 4; j++)
                u1[j] = xhl[j * 432 + base + 74];       // tap 8 (dy=2,dx=2)
            Xh1 = unpack_lo4(u1);
            Xl1 = unpack_hi4(u1);
        }
        f32x4 d0, d1;
#pragma unroll
        for (int j = 0; j < 4; j++) { d0[j] = bias1[j]; d1[j] = bias1[4 + j]; }
        d0 = __builtin_amdgcn_mfma_f32_16x16x32_f16(Wf[0], Xh0, d0, 0, 0, 0);
        d0 = __builtin_amdgcn_mfma_f32_16x16x32_f16(Wf[0], Xl0, d0, 0, 0, 0);
        d0 = __builtin_amdgcn_mfma_f32_16x16x32_f16(Wf[1], Xh0, d0, 0, 0, 0);
        d0 = __builtin_amdgcn_mfma_f32_16x16x32_f16(Wf[4], Xh1, d0, 0, 0, 0);
        d0 = __builtin_amdgcn_mfma_f32_16x16x32_f16(Wf[4], Xl1, d0, 0, 0, 0);
        d0 = __builtin_amdgcn_mfma_f32_16x16x32_f16(Wf[5], Xh1, d0, 0, 0, 0);
        d1 = __builtin_amdgcn_mfma_f32_16x16x32_f16(Wf[2], Xh0, d1, 0, 0, 0);
        d1 = __builtin_amdgcn_mfma_f32_16x16x32_f16(Wf[2], Xl0, d1, 0, 0, 0);
        d1 = __builtin_amdgcn_mfma_f32_16x16x32_f16(Wf[3], Xh0, d1, 0, 0, 0);
        d1 = __builtin_amdgcn_mfma_f32_16x16x32_f16(Wf[6], Xh1, d1, 0, 0, 0);
        d1 = __builtin_amdgcn_mfma_f32_16x16x32_f16(Wf[6], Xl1, d1, 0, 0, 0);
        d1 = __builtin_amdgcn_mfma_f32_16x16x32_f16(Wf[7], Xh1, d1, 0, 0, 0);
        if (valid) {
            int sw = (cx & 7) << 4;
            char* pxb = f1t + ry * 4352 + cx * 128;
#pragma unroll
            for (int h = 0; h < 2; h++) {
                f32x4 d = h ? d1 : d0;
                half4 hq, lq;
#pragma unroll
                for (int j = 0; j < 4; j++) {
                    float v = d[j];
                    v = fmaxf(v, 0.2f * v);
                    v = ok ? v : 0.f;
                    _Float16 hv = (_Float16)v;
                    hq[j] = hv;
                    lq[j] = (_Float16)(v - (float)hv);
                }
                int q8 = (h * 4 + cg) * 8;
                *(half4*)(pxb + (q8 ^ sw)) = hq;
                *(half4*)(pxb + ((64 + q8) ^ sw)) = lq;
            }
        }
    }
    __syncthreads();

    // phase 3: conv2 via rolling-row f16x2 MFMA, operands swapped: D = W*X
    int wx = wid & 1, wy = wid >> 1;
    f32x4 acc2[4];
#pragma unroll
    for (int r = 0; r < 4; r++) acc2[r] = binit;
#pragma unroll
    for (int iy = 0; iy < 6; iy++) {
        int f1row = wy * 4 + iy;
        half8 ah[3], al[3];
#pragma unroll
        for (int kx = 0; kx < 3; kx++) {
            int pxi = wx * 16 + m + kx;
            int base = f1row * 4352 + pxi * 128;
            int sw = (pxi & 7) << 4;
            ah[kx] = *(const half8*)(f1t + base + ((b * 16) ^ sw));
            al[kx] = *(const half8*)(f1t + base + ((64 + b * 16) ^ sw));
        }
#pragma unroll
        for (int kx = 0; kx < 3; kx++) {
#pragma unroll
            for (int ry = 0; ry < 4; ry++) {
                if (ry >= iy - 2 && ry <= iy) {
                    const int t = (iy - ry) * 3 + kx;
                    acc2[ry] = __builtin_amdgcn_mfma_f32_16x16x32_f16(Bh[t], ah[kx], acc2[ry], 0, 0, 0);
                    acc2[ry] = __builtin_amdgcn_mfma_f32_16x16x32_f16(Bl[t], ah[kx], acc2[ry], 0, 0, 0);
                    acc2[ry] = __builtin_amdgcn_mfma_f32_16x16x32_f16(Bh[t], al[kx], acc2[ry], 0, 0, 0);
                }
            }
        }
    }

    // epilogue (h-only f2n): leaky -> f16 -> direct store, 32B/px
    int x0 = bx + wx * 16 + m;
    int y0 = by + wy * 4;
    int co_off = b * 4;
#pragma unroll
    for (int ry = 0; ry < 4; ry++) {
        half4 hq;
#pragma unroll
        for (int j = 0; j < 4; j++) {
            float v = acc2[ry][j];
            v = fmaxf(v, 0.2f * v);
            hq[j] = (_Float16)v;
        }
        *(half4*)(f2n + ((size_t)(y0 + ry) * W + x0) * 16 + co_off) = hq;
    }
}

// ---------------- conv3 v3: h-only f2n input, 32x8 tile ----------------
// Probe: X = f16(f2) (data residual dropped); weight residual terms kept.
__global__ __launch_bounds__(256) void conv3_mfma(const _Float16* __restrict__ f2n,
                                                  const _Float16* __restrict__ w3f,
                                                  const float* __restrict__ bias,
                                                  float* __restrict__ f3) {
    __shared__ __align__(16) char st[10 * 34 * 40];    // 13600 B
    int tid = threadIdx.x;
    int lane = tid & 63;
    int wid = tid >> 6;
    int bx = blockIdx.x * 32, by = blockIdx.y * 8;

    // stage: rows by-1..by+8, px bx-1..bx+32, 2 x 16B chunks per px (680 tasks)
    for (int idx = tid; idx < 680; idx += 256) {
        int c0 = idx & 1;
        int rp = idx >> 1;
        int r = rp / 34, p = rp - r * 34;
        int gy = by + r - 1, gx = bx + p - 1;
        half8 v = {0, 0, 0, 0, 0, 0, 0, 0};
        if ((unsigned)gy < H && (unsigned)gx < W)
            v = *(const half8*)(f2n + ((size_t)gy * W + gx) * 16 + c0 * 8);
        *(half8*)(st + r * 1360 + p * 40 + c0 * 16) = v;
    }

    half8 F[12];
#pragma unroll
    for (int t = 0; t < 12; t++)
        F[t] = *(const half8*)(w3f + (t * 64 + lane) * 8);
    int m = lane & 15, b = lane >> 4;
    int halfco = b & 1, kxp = b >> 1;
    int wx = wid & 1, wy = wid >> 1;
    float bc = (m < 8) ? bias[m] : 0.f;
    f32x4 acc[4];
#pragma unroll
    for (int r = 0; r < 4; r++) acc[r] = (f32x4){bc, bc, bc, bc};
    int pA = wx * 16 + m + kxp;                        // halo-local px for A (kx -1,0)
    int pB = wx * 16 + m + 2;                          // halo-local px for B (kx +1)
    __syncthreads();

#pragma unroll
    for (int iy = 0; iy < 6; iy++) {
        const char* rp = st + (wy * 4 + iy) * 1360;
        half8 ka_h = *(const half8*)(rp + pA * 40 + halfco * 16);
        half8 kb_h = *(const half8*)(rp + pB * 40 + halfco * 16);
#pragma unroll
        for (int ry = 0; ry < 4; ry++) {
            if (ry >= iy - 2 && ry <= iy) {
                const int ky = iy - ry;
                acc[ry] = __builtin_amdgcn_mfma_f32_16x16x32_f16(ka_h, F[ky * 4 + 0], acc[ry], 0, 0, 0);
                acc[ry] = __builtin_amdgcn_mfma_f32_16x16x32_f16(ka_h, F[ky * 4 + 1], acc[ry], 0, 0, 0);
                acc[ry] = __builtin_amdgcn_mfma_f32_16x16x32_f16(kb_h, F[ky * 4 + 2], acc[ry], 0, 0, 0);
                acc[ry] = __builtin_amdgcn_mfma_f32_16x16x32_f16(kb_h, F[ky * 4 + 3], acc[ry], 0, 0, 0);
            }
        }
    }

    if (m < 8) {
#pragma unroll
        for (int ry = 0; ry < 4; ry++) {
            int y = by + wy * 4 + ry;
            *(float4*)(f3 + (size_t)m * HW + (size_t)y * W + bx + wx * 16 + b * 4) =
                make_float4(acc[ry][0], acc[ry][1], acc[ry][2], acc[ry][3]);
        }
    }
}

// ---------------- stdfuse (fused v4): SAT-y phase 3 ----------------
// Vertical window sums via column-wise inclusive prefix over hsq: 4 loads + 8 subs
// per window pair instead of (wlen+1) loads + ~wlen*4 adds.
__global__ __launch_bounds__(256) void stdfuse_fused(const float* __restrict__ f3all,
                                                     const float* __restrict__ fw,
                                                     const float* __restrict__ fb,
                                                     const float* __restrict__ stats,
                                                     float* __restrict__ out) {
    __shared__ __align__(16) float raw[46 * 50];
    __shared__ __align__(16) float hsq[3][46 * 76];
    __shared__ int rowOff[46];      // reflected gy * W (element offset)
    __shared__ int gxcol[46];       // reflected gx
    int tid = threadIdx.x;
    int xq = tid & 15, yp = tid >> 4;
    int bx = blockIdx.x * 32, by = blockIdx.y * 32;
    int batch = blockIdx.z;
    const float* f3 = f3all + (size_t)batch * 8 * HW;

    if (tid < 46) {
        int gy = by + tid - 7;
        gy = gy < 0 ? -gy : (gy > 1023 ? 2046 - gy : gy);
        rowOff[tid] = gy * W;
        int gx = bx + tid - 7;
        gx = gx < 0 ? -gx : (gx > 1023 ? 2046 - gx : gx);
        gxcol[tid] = gx;
    }
    __syncthreads();

    // per-thread staging task table (channel-invariant): 2116 = 8*256 + 68 tasks
    int goffB[9];   // global byte offset within a channel plane
    int laddB[9];   // LDS byte offset into raw
    const bool k8 = tid < 68;
#pragma unroll
    for (int k = 0; k < 9; k++) {
        int idx = tid + k * 256;
        int idc = idx < 2116 ? idx : 2115;
        int r = idc / 46, c = idc - r * 46;
        goffB[k] = (rowOff[r] + gxcol[c]) * 4;
        laddB[k] = (r * 50 + c) * 4;
    }

    float wwin[3] = {fw[0] * 0.125f, fw[1] * 0.125f, fw[2] * 0.125f};
    float part[4] = {0.f, 0.f, 0.f, 0.f};

    // prologue: load channel 0 into registers
    float stg[9];
    {
        const char* src = (const char*)f3;
#pragma unroll
        for (int k = 0; k < 8; k++) stg[k] = *(const float*)(src + goffB[k]);
        stg[8] = k8 ? *(const float*)(src + goffB[8]) : 0.f;
    }

    for (int z = 0; z < 8; z++) {
        // write staged registers to raw (safe: prior phase-2 raw reads ended at barrier B)
        char* rb = (char*)raw;
#pragma unroll
        for (int k = 0; k < 8; k++) *(float*)(rb + laddB[k]) = stg[k];
        if (k8) *(float*)(rb + laddB[8]) = stg[8];

        // T14: issue next channel's loads BEFORE the barrier; latency hides under phase 2+3
        if (z < 7) {
            const char* nsrc = (const char*)(f3 + (size_t)(z + 1) * HW);
#pragma unroll
            for (int k = 0; k < 8; k++) stg[k] = *(const float*)(nsrc + goffB[k]);
            if (k8) stg[8] = *(const float*)(nsrc + goffB[8]);
        }
        __syncthreads();   // A: raw ready; prior phase-3 hsq reads complete

        // phase 2: horizontal window sums (s, q) for A/B pixel pairs, all 46 rows
        for (int idx = tid; idx < 736; idx += 256) {
            int r = idx >> 4, xh = idx & 15;
            const float* rp = raw + r * 50 + 2 * xh;
            float v[16], w[16];
#pragma unroll
            for (int k = 0; k < 8; k++) {
                float2 p = *(const float2*)(rp + 2 * k);
                v[2 * k] = p.x; v[2 * k + 1] = p.y;
            }
#pragma unroll
            for (int k = 0; k < 16; k++) w[k] = v[k] * v[k];
            float ms = v[6] + v[7] + v[8] + v[9];
            float mq = w[6] + w[7] + w[8] + w[9];
            float sA5 = v[5] + ms, sB5 = ms + v[10];
            float qA5 = w[5] + mq, qB5 = mq + w[10];
            float sA9 = sA5 + v[3] + v[4] + v[10] + v[11];
            float sB9 = sB5 + v[4] + v[5] + v[11] + v[12];
            float qA9 = qA5 + w[3] + w[4] + w[10] + w[11];
            float qB9 = qB5 + w[4] + w[5] + w[11] + w[12];
            float sA15 = sA9 + v[0] + v[1] + v[2] + v[12] + v[13] + v[14];
            float sB15 = sB9 + v[1] + v[2] + v[3] + v[13] + v[14] + v[15];
            float qA15 = qA9 + w[0] + w[1] + w[2] + w[12] + w[13] + w[14];
            float qB15 = qB9 + w[1] + w[2] + w[3] + w[13] + w[14] + w[15];
            int base = r * 76 + 4 * xh;
            *(float4*)&hsq[0][base] = make_float4(sA5, qA5, sB5, qB5);
            *(float4*)&hsq[1][base] = make_float4(sA9, qA9, sB9, qB9);
            *(float4*)&hsq[2][base] = make_float4(sA15, qA15, sB15, qB15);
        }
        __syncthreads();   // B: hsq ready; all raw reads complete

        // phase 2.5: column-wise inclusive prefix over the 46 rows (192 threads)
        if (tid < 192) {
            int wi = tid >> 6, c = tid & 63;
            float* col = &hsq[wi][c];
            float run = col[0];
#pragma unroll 5
            for (int r = 1; r < 46; r++) {
                run += col[r * 76];
                col[r * 76] = run;
            }
        }
        __syncthreads();   // C: prefix ready

        // phase 3: window sums from 4 prefix rows per window
#pragma unroll
        for (int wi = 0; wi < 3; wi++) {
            const int wlen = (wi == 0) ? 5 : ((wi == 1) ? 9 : 15);
            const int r0 = 2 * yp + 7 - (wlen >> 1);
            const float inv = 1.0f / (float)(wlen * wlen);
            const float ww = wwin[wi];
            const float* basep = &hsq[wi][4 * xq];
            float4 Pa;
            if (wi == 2 && yp == 0) Pa = make_float4(0.f, 0.f, 0.f, 0.f);
            else Pa = *(const float4*)(basep + (r0 - 1) * 76);
            float4 Pb = *(const float4*)(basep + (r0 + wlen - 1) * 76);
            float4 Pc = *(const float4*)(basep + r0 * 76);
            float4 Pd = *(const float4*)(basep + (r0 + wlen) * 76);
            float sA0 = Pb.x - Pa.x, qA0 = Pb.y - Pa.y;
            float sB0 = Pb.z - Pa.z, qB0 = Pb.w - Pa.w;
            float sA1 = Pd.x - Pc.x, qA1 = Pd.y - Pc.y;
            float sB1 = Pd.z - Pc.z, qB1 = Pd.w - Pc.w;
            float mA0 = sA0 * inv, m2A0 = qA0 * inv;
            part[0] += ww * fast_sqrtf(fmaxf(m2A0 - mA0 * mA0, 0.f) + 1e-8f);
            float mB0 = sB0 * inv, m2B0 = qB0 * inv;
            part[1] += ww * fast_sqrtf(fmaxf(m2B0 - mB0 * mB0, 0.f) + 1e-8f);
            float mA1 = sA1 * inv, m2A1 = qA1 * inv;
            part[2] += ww * fast_sqrtf(fmaxf(m2A1 - mA1 * mA1, 0.f) + 1e-8f);
            float mB1 = sB1 * inv, m2B1 = qB1 * inv;
            part[3] += ww * fast_sqrtf(fmaxf(m2B1 - mB1 * mB1, 0.f) + 1e-8f);
        }
        // no barrier: next iter writes raw (disjoint from hsq); hsq rewritten only after next barrier A
    }

    // epilogue: fused value -> per-channel threshold + sigmoid, direct output write
    float fb0 = fb[0];
    int gy = by + 2 * yp, gx = bx + 2 * xq;
#pragma unroll
    for (int c = 0; c < 4; c++) {
        float lo = stats[(batch * 4 + c) * 2];
        float up = stats[(batch * 4 + c) * 2 + 1];
        float inv = 1.f / (up - lo);
        float v[4];
#pragma unroll
        for (int p = 0; p < 4; p++) {
            float ns = (part[p] + fb0 - lo) * inv;
            ns = fminf(fmaxf(ns, 0.f), 1.f);
            v[p] = 1.f / (1.f + fast_expf(3.f - 6.f * ns));
        }
        float* plane = out + ((size_t)(batch * 4 + c)) * HW;
        *(float2*)(plane + (size_t)gy * W + gx) = make_float2(v[0], v[1]);
        *(float2*)(plane + (size_t)(gy + 1) * W + gx) = make_float2(v[2], v[3]);
    }
}

extern "C" void kernel_launch(void* const* d_in, const int* in_sizes, int n_in,
                              void* d_out, int out_size, void* d_ws, size_t ws_size,
                              hipStream_t stream) {
    (void)in_sizes; (void)n_in; (void)out_size; (void)ws_size;
    const float* x = (const float*)d_in[0];
    const float* w1 = (const float*)d_in[1];
    const float* b1 = (const float*)d_in[2];
    const float* w2 = (const float*)d_in[3];
    const float* b2 = (const float*)d_in[4];
    const float* w3 = (const float*)d_in[5];
    const float* b3 = (const float*)d_in[6];
    const float* chw = (const float*)d_in[7];
    const float* fw = (const float*)d_in[8];
    const float* fb = (const float*)d_in[9];
    float* out = (float*)d_out;

    char* ws = (char*)d_ws;
    float* stats = (float*)ws;                         // 32 f
    double* part = (double*)(ws + 256);                // 1024 d, ends 8448
    _Float16* w1a = (_Float16*)(ws + 8448);            // 4096 f16, ends 16640
    _Float16* w3f = (_Float16*)(ws + 24832);           // 6144 f16, ends 37120
    _Float16* w2bh = (_Float16*)(ws + 37120);          // 4608 f16, ends 46336
    _Float16* w2bl = (_Float16*)(ws + 46336);          // 4608 f16, ends 55552
    float* f3all = (float*)(ws + 65536);               // 4 batches x 8 ch x HW f32 = 128 MB
    _Float16* f2n = (_Float16*)(ws + 134283264);       // 32 MB h-only (reused per batch)

    stats_partial<<<512, 256, 0, stream>>>(x, part);
    stats_final_prep<<<1, 256, 0, stream>>>(part, chw, w1, w2, w3, stats, w1a, w3f, w2bh, w2bl);

    for (int b = 0; b < 4; b++) {
        const float* xb = x + (size_t)b * 4 * HW;
        conv12_mfma<<<dim3(32, 128), 256, 0, stream>>>(xb, w1a, b1, w2bh, w2bl, b2, f2n);
        conv3_mfma<<<dim3(32, 128), 256, 0, stream>>>(f2n, w3f, b3, f3all + (size_t)b * 8 * HW);
    }
    stdfuse_fused<<<dim3(32, 32, 4), 256, 0, stream>>>(f3all, fw, fb, stats, out);
}

// Round 7
// 425.100 us; speedup vs baseline: 1.2215x; 1.2215x over previous
//
#include <hip/hip_runtime.h>
#include <math.h>

#define H 1024
#define W 1024
#define HW (H * W)

typedef _Float16 half8 __attribute__((ext_vector_type(8)));
typedef _Float16 half4 __attribute__((ext_vector_type(4)));
typedef float f32x4 __attribute__((ext_vector_type(4)));
typedef unsigned uint4v __attribute__((ext_vector_type(4)));

__device__ __forceinline__ float fast_sqrtf(float x) { return __builtin_amdgcn_sqrtf(x); }
__device__ __forceinline__ float fast_expf(float x) { return __builtin_amdgcn_exp2f(x * 1.44269504088896340736f); }

union U16 { unsigned short u; _Float16 f; };

// assemble half8 of the low-16 halves of 8 packed u32 via v_perm_b32
__device__ __forceinline__ half8 unpack_lo8(const unsigned* u) {
    uint4v a;
    a.x = __builtin_amdgcn_perm(u[1], u[0], 0x05040100);
    a.y = __builtin_amdgcn_perm(u[3], u[2], 0x05040100);
    a.z = __builtin_amdgcn_perm(u[5], u[4], 0x05040100);
    a.w = __builtin_amdgcn_perm(u[7], u[6], 0x05040100);
    return __builtin_bit_cast(half8, a);
}
__device__ __forceinline__ half8 unpack_lo4(const unsigned* u) {
    uint4v a;
    a.x = __builtin_amdgcn_perm(u[1], u[0], 0x05040100);
    a.y = __builtin_amdgcn_perm(u[3], u[2], 0x05040100);
    a.z = 0; a.w = 0;
    return __builtin_bit_cast(half8, a);
}

// ---------------- stats pass 1: partial sum/sumsq per (b,c) chunk ----------------
__global__ __launch_bounds__(256) void stats_partial(const float* __restrict__ x,
                                                     double* __restrict__ part) {
    int blk = blockIdx.x;
    int bc = blk >> 5;
    int j = blk & 31;
    const float* p = x + (size_t)bc * HW + (size_t)j * (HW / 32);
    int tid = threadIdx.x;
    double s = 0.0, q = 0.0;
    const float4* p4 = (const float4*)p;
    for (int i = tid; i < (HW / 32) / 4; i += 256) {
        float4 v = p4[i];
        s += (double)v.x + (double)v.y + (double)v.z + (double)v.w;
        q += (double)v.x * v.x + (double)v.y * v.y + (double)v.z * v.z + (double)v.w * v.w;
    }
    __shared__ double ls[256], lq[256];
    ls[tid] = s;
    lq[tid] = q;
    __syncthreads();
    for (int ofs = 128; ofs > 0; ofs >>= 1) {
        if (tid < ofs) { ls[tid] += ls[tid + ofs]; lq[tid] += lq[tid + ofs]; }
        __syncthreads();
    }
    if (tid == 0) {
        part[blk * 2] = ls[0];
        part[blk * 2 + 1] = lq[0];
    }
}

// ---------------- stats pass 2 + weight prep (h-only conv weights) ----------------
__global__ __launch_bounds__(256) void stats_final_prep(const double* __restrict__ part,
                                                        const float* __restrict__ chw,
                                                        const float* __restrict__ w1,
                                                        const float* __restrict__ w2,
                                                        const float* __restrict__ w3,
                                                        float* __restrict__ stats,
                                                        _Float16* __restrict__ w1a,
                                                        _Float16* __restrict__ w3f,
                                                        _Float16* __restrict__ w2bh) {
    int tid = threadIdx.x;
    __shared__ float cw[4];
    if (tid == 0) {
        float m = fmaxf(fmaxf(chw[0], chw[1]), fmaxf(chw[2], chw[3]));
        float e0 = expf(chw[0] - m), e1 = expf(chw[1] - m);
        float e2 = expf(chw[2] - m), e3 = expf(chw[3] - m);
        float s = e0 + e1 + e2 + e3;
        cw[0] = e0 / s; cw[1] = e1 / s; cw[2] = e2 / s; cw[3] = e3 / s;
    }
    __syncthreads();
    if (tid < 16) {
        double s = 0.0, q = 0.0;
        for (int j = 0; j < 32; j++) {
            s += part[(tid * 32 + j) * 2];
            q += part[(tid * 32 + j) * 2 + 1];
        }
        double n = (double)HW;
        double var = (q - s * s / n) / (n - 1.0);
        if (var < 0) var = 0;
        float gs = (float)sqrt(var);
        int c = tid & 3;
        float gf = fminf(fmaxf(gs * 5.0f, 0.5f), 2.0f);
        float cf = fminf(fmaxf(gs * cw[c] * 2.0f, 0.8f), 1.2f);
        stats[tid * 2] = 0.05f * gf * cf;
        stats[tid * 2 + 1] = 0.20f * gf * cf;
    }
    // conv1 A-frags, h-only: 4 sets (c,h) of 64 lanes x 8
    for (int i = tid; i < 256; i += 256) {
        int s = i >> 6, l = i & 63;
        int c = s >> 1, h = s & 1;
        int m = l & 15, cg = l >> 4;
        int co = h * 16 + m;
#pragma unroll
        for (int j = 0; j < 8; j++) {
            int k = c * 32 + cg * 8 + j;
            float v = 0.f;
            if (k < 36) {
                int t = k >> 2, ci = k & 3;
                v = w1[(co * 4 + ci) * 9 + t];
            }
            w1a[i * 8 + j] = (_Float16)v;
        }
    }
    for (int idx = tid; idx < 576; idx += 256) {           // conv2 B-frags (h only)
        int t = idx >> 6, l = idx & 63;
        int co = l & 15, cg = l >> 4;
#pragma unroll
        for (int j = 0; j < 8; j++) {
            int ci = cg * 8 + j;
            w2bh[idx * 8 + j] = (_Float16)w2[(co * 32 + ci) * 9 + t];
        }
    }
    for (int idx = tid; idx < 384; idx += 256) {           // conv3 B-frags: 6 sets (ky,grp) h-only
        int t = idx >> 6, l = idx & 63;
        int ky = t / 2, grp = t & 1;
        int co = l & 15, bq = l >> 4;
#pragma unroll
        for (int j = 0; j < 8; j++) {
            int k = bq * 8 + j;
            float v = 0.f;
            if (co < 8) {
                if (grp == 0) {
                    int kxp = k >> 4, ci = k & 15;
                    v = w3[((co * 16 + ci) * 3 + ky) * 3 + kxp];
                } else if (k < 16) {
                    v = w3[((co * 16 + k) * 3 + ky) * 3 + 2];
                }
            }
            w3f[idx * 8 + j] = (_Float16)v;
        }
    }
}

// ---------------- fused conv1+conv2, f16 h-only MFMA ----------------
// v7: all low-half (residual) terms dropped -- MFMA volume /3, f1t 80B/px h-only,
// LDS 34.1 KB -> 4 blocks/CU.
__global__ __launch_bounds__(256, 4) void conv12_mfma(const float* __restrict__ x,
                                                      const _Float16* __restrict__ w1a,
                                                      const float* __restrict__ b1,
                                                      const _Float16* __restrict__ wbh,
                                                      const float* __restrict__ b2,
                                                      _Float16* __restrict__ f2n) {
    __shared__ __align__(16) char smem[34112];
    char* f1t = smem;                                  // 10*34*80 = 27200 B (h-only)
    unsigned* xhl = (unsigned*)(smem + 27200);         // [4][12][36] u32 (f16 h in low16)
    int tid = threadIdx.x;
    int lane = tid & 63;
    int wid = tid >> 6;
    int bx = blockIdx.x * 32, by = blockIdx.y * 8;
    int n = lane & 15, cg = lane >> 4;
    int m = lane & 15, b = lane >> 4;

    // phase 1: stage x halo (rows by-2..by+9, cols bx-2..bx+33) as f16 (low half of u32)
    {
        int idx = tid;
        int r = tid / 36, c = tid - r * 36, ci = 0;
#pragma unroll
        for (int it = 0; it < 7; ++it) {
            if (idx < 1728) {
                int gy = by + r - 2, gx = bx + c - 2;
                float v = 0.f;
                if ((unsigned)gy < H && (unsigned)gx < W) v = x[ci * HW + gy * W + gx];
                U16 a; a.f = (_Float16)v;
                xhl[idx] = (unsigned)a.u;
            }
            idx += 256;
            c += 4; if (c >= 36) { c -= 36; r += 1; }
            r += 7; if (r >= 12) { r -= 12; ci += 1; }
        }
    }

    // weight frags (h-only): Wc0h0, Wc0h1, Wc1h0, Wc1h1
    half8 Wf00 = *(const half8*)(w1a + (0 * 64 + lane) * 8);
    half8 Wf01 = *(const half8*)(w1a + (1 * 64 + lane) * 8);
    half8 Wf10 = *(const half8*)(w1a + (2 * 64 + lane) * 8);
    half8 Wf11 = *(const half8*)(w1a + (3 * 64 + lane) * 8);
    float bias1[8];
#pragma unroll
    for (int h = 0; h < 2; h++)
#pragma unroll
        for (int j = 0; j < 4; j++)
            bias1[h * 4 + j] = b1[h * 16 + cg * 4 + j];
    // conv2 weights hoisted: latency hides under conv1
    half8 Bh[9];
#pragma unroll
    for (int t = 0; t < 9; t++)
        Bh[t] = *(const half8*)(wbh + (t * 64 + lane) * 8);
    f32x4 binit;
#pragma unroll
    for (int j = 0; j < 4; j++) binit[j] = b2[b * 4 + j];

    int t0 = 2 * cg, t1 = 2 * cg + 1;
    int dy0 = (t0 * 11) >> 5, dx0 = t0 - 3 * dy0;
    int dy1 = (t1 * 11) >> 5, dx1 = t1 - 3 * dy1;
    int off0 = dy0 * 36 + dx0, off1 = dy1 * 36 + dx1;
    __syncthreads();

    // phase 2: conv1 via MFMA; 22 tiles of 16 px cover the 340-px halo
#pragma unroll 1
    for (int tt = wid; tt < 22; tt += 4) {
        int p = tt * 16 + n;
        bool valid = p < 340;
        int pc = valid ? p : 339;
        int ry = pc / 34, cx = pc - ry * 34;
        int gy = by + ry - 1, gx = bx + cx - 1;
        bool ok = ((unsigned)gy < H) && ((unsigned)gx < W);
        int base = ry * 36 + cx;
        unsigned u0[8];
#pragma unroll
        for (int j = 0; j < 8; j++)
            u0[j] = xhl[(j & 3) * 432 + base + ((j < 4) ? off0 : off1)];
        half8 Xh0 = unpack_lo8(u0);
        half8 Xh1 = {0, 0, 0, 0, 0, 0, 0, 0};
        if (cg == 0) {
            unsigned u1[4];
#pragma unroll
            for (int j = 0; j < 4; j++)
                u1[j] = xhl[j * 432 + base + 74];       // tap 8 (dy=2,dx=2)
            Xh1 = unpack_lo4(u1);
        }
        f32x4 d0, d1;
#pragma unroll
        for (int j = 0; j < 4; j++) { d0[j] = bias1[j]; d1[j] = bias1[4 + j]; }
        d0 = __builtin_amdgcn_mfma_f32_16x16x32_f16(Wf00, Xh0, d0, 0, 0, 0);
        d0 = __builtin_amdgcn_mfma_f32_16x16x32_f16(Wf10, Xh1, d0, 0, 0, 0);
        d1 = __builtin_amdgcn_mfma_f32_16x16x32_f16(Wf01, Xh0, d1, 0, 0, 0);
        d1 = __builtin_amdgcn_mfma_f32_16x16x32_f16(Wf11, Xh1, d1, 0, 0, 0);
        if (valid) {
            char* pxb = f1t + ry * 2720 + cx * 80;
#pragma unroll
            for (int h = 0; h < 2; h++) {
                f32x4 d = h ? d1 : d0;
                half4 hq;
#pragma unroll
                for (int j = 0; j < 4; j++) {
                    float v = d[j];
                    v = fmaxf(v, 0.2f * v);
                    v = ok ? v : 0.f;
                    hq[j] = (_Float16)v;
                }
                *(half4*)(pxb + (h * 4 + cg) * 8) = hq;
            }
        }
    }
    __syncthreads();

    // phase 3: conv2 via rolling-row f16 MFMA, D = W*X (lane owns px, 4 co)
    int wx = wid & 1, wy = wid >> 1;
    f32x4 acc2[4];
#pragma unroll
    for (int r = 0; r < 4; r++) acc2[r] = binit;
#pragma unroll
    for (int iy = 0; iy < 6; iy++) {
        int f1row = wy * 4 + iy;
        half8 ah[3];
#pragma unroll
        for (int kx = 0; kx < 3; kx++) {
            int pxi = wx * 16 + m + kx;
            ah[kx] = *(const half8*)(f1t + f1row * 2720 + pxi * 80 + b * 16);
        }
#pragma unroll
        for (int kx = 0; kx < 3; kx++) {
#pragma unroll
            for (int ry = 0; ry < 4; ry++) {
                if (ry >= iy - 2 && ry <= iy) {
                    const int t = (iy - ry) * 3 + kx;
                    acc2[ry] = __builtin_amdgcn_mfma_f32_16x16x32_f16(Bh[t], ah[kx], acc2[ry], 0, 0, 0);
                }
            }
        }
    }

    // epilogue (h-only f2n): leaky -> f16 -> direct store, 32B/px
    int x0 = bx + wx * 16 + m;
    int y0 = by + wy * 4;
    int co_off = b * 4;
#pragma unroll
    for (int ry = 0; ry < 4; ry++) {
        half4 hq;
#pragma unroll
        for (int j = 0; j < 4; j++) {
            float v = acc2[ry][j];
            v = fmaxf(v, 0.2f * v);
            hq[j] = (_Float16)v;
        }
        *(half4*)(f2n + ((size_t)(y0 + ry) * W + x0) * 16 + co_off) = hq;
    }
}

// ---------------- conv3: h-only f16 MFMA, 32x8 tile ----------------
__global__ __launch_bounds__(256) void conv3_mfma(const _Float16* __restrict__ f2n,
                                                  const _Float16* __restrict__ w3f,
                                                  const float* __restrict__ bias,
                                                  float* __restrict__ f3) {
    __shared__ __align__(16) char st[10 * 34 * 40];    // 13600 B
    int tid = threadIdx.x;
    int lane = tid & 63;
    int wid = tid >> 6;
    int bx = blockIdx.x * 32, by = blockIdx.y * 8;

    // stage: rows by-1..by+8, px bx-1..bx+32, 2 x 16B chunks per px (680 tasks)
    for (int idx = tid; idx < 680; idx += 256) {
        int c0 = idx & 1;
        int rp = idx >> 1;
        int r = rp / 34, p = rp - r * 34;
        int gy = by + r - 1, gx = bx + p - 1;
        half8 v = {0, 0, 0, 0, 0, 0, 0, 0};
        if ((unsigned)gy < H && (unsigned)gx < W)
            v = *(const half8*)(f2n + ((size_t)gy * W + gx) * 16 + c0 * 8);
        *(half8*)(st + r * 1360 + p * 40 + c0 * 16) = v;
    }

    half8 F0[3], F1[3];                                // per ky: grp0-h, grp1-h
#pragma unroll
    for (int ky = 0; ky < 3; ky++) {
        F0[ky] = *(const half8*)(w3f + ((ky * 2 + 0) * 64 + lane) * 8);
        F1[ky] = *(const half8*)(w3f + ((ky * 2 + 1) * 64 + lane) * 8);
    }
    int m = lane & 15, b = lane >> 4;
    int halfco = b & 1, kxp = b >> 1;
    int wx = wid & 1, wy = wid >> 1;
    float bc = (m < 8) ? bias[m] : 0.f;
    f32x4 acc[4];
#pragma unroll
    for (int r = 0; r < 4; r++) acc[r] = (f32x4){bc, bc, bc, bc};
    int pA = wx * 16 + m + kxp;                        // halo-local px for A (kx -1,0)
    int pB = wx * 16 + m + 2;                          // halo-local px for B (kx +1)
    __syncthreads();

#pragma unroll
    for (int iy = 0; iy < 6; iy++) {
        const char* rp = st + (wy * 4 + iy) * 1360;
        half8 ka_h = *(const half8*)(rp + pA * 40 + halfco * 16);
        half8 kb_h = *(const half8*)(rp + pB * 40 + halfco * 16);
#pragma unroll
        for (int ry = 0; ry < 4; ry++) {
            if (ry >= iy - 2 && ry <= iy) {
                const int ky = iy - ry;
                acc[ry] = __builtin_amdgcn_mfma_f32_16x16x32_f16(ka_h, F0[ky], acc[ry], 0, 0, 0);
                acc[ry] = __builtin_amdgcn_mfma_f32_16x16x32_f16(kb_h, F1[ky], acc[ry], 0, 0, 0);
            }
        }
    }

    if (m < 8) {
#pragma unroll
        for (int ry = 0; ry < 4; ry++) {
            int y = by + wy * 4 + ry;
            *(float4*)(f3 + (size_t)m * HW + (size_t)y * W + bx + wx * 16 + b * 4) =
                make_float4(acc[ry][0], acc[ry][1], acc[ry][2], acc[ry][3]);
        }
    }
}

// ---------------- stdfuse (round-5 proven version): 8-channel std + fusion + sigmoid ----------------
__global__ __launch_bounds__(256) void stdfuse_fused(const float* __restrict__ f3all,
                                                     const float* __restrict__ fw,
                                                     const float* __restrict__ fb,
                                                     const float* __restrict__ stats,
                                                     float* __restrict__ out) {
    __shared__ __align__(16) float raw[46 * 50];
    __shared__ __align__(16) float hsq[3][46 * 76];
    __shared__ int rowOff[46];      // reflected gy * W (element offset)
    __shared__ int gxcol[46];       // reflected gx
    int tid = threadIdx.x;
    int xq = tid & 15, yp = tid >> 4;
    int bx = blockIdx.x * 32, by = blockIdx.y * 32;
    int batch = blockIdx.z;
    const float* f3 = f3all + (size_t)batch * 8 * HW;

    if (tid < 46) {
        int gy = by + tid - 7;
        gy = gy < 0 ? -gy : (gy > 1023 ? 2046 - gy : gy);
        rowOff[tid] = gy * W;
        int gx = bx + tid - 7;
        gx = gx < 0 ? -gx : (gx > 1023 ? 2046 - gx : gx);
        gxcol[tid] = gx;
    }
    __syncthreads();

    // per-thread staging task table (channel-invariant): 2116 = 8*256 + 68 tasks
    int goffB[9];   // global byte offset within a channel plane
    int laddB[9];   // LDS byte offset into raw
    const bool k8 = tid < 68;
#pragma unroll
    for (int k = 0; k < 9; k++) {
        int idx = tid + k * 256;
        int idc = idx < 2116 ? idx : 2115;
        int r = idc / 46, c = idc - r * 46;
        goffB[k] = (rowOff[r] + gxcol[c]) * 4;
        laddB[k] = (r * 50 + c) * 4;
    }

    float wwin[3] = {fw[0] * 0.125f, fw[1] * 0.125f, fw[2] * 0.125f};
    float part[4] = {0.f, 0.f, 0.f, 0.f};

    // prologue: load channel 0 into registers
    float stg[9];
    {
        const char* src = (const char*)f3;
#pragma unroll
        for (int k = 0; k < 8; k++) stg[k] = *(const float*)(src + goffB[k]);
        stg[8] = k8 ? *(const float*)(src + goffB[8]) : 0.f;
    }

    for (int z = 0; z < 8; z++) {
        // write staged registers to raw (safe: prior phase-2 raw reads ended at barrier B)
        char* rb = (char*)raw;
#pragma unroll
        for (int k = 0; k < 8; k++) *(float*)(rb + laddB[k]) = stg[k];
        if (k8) *(float*)(rb + laddB[8]) = stg[8];

        // T14: issue next channel's loads BEFORE the barrier; latency hides under phase 2+3
        if (z < 7) {
            const char* nsrc = (const char*)(f3 + (size_t)(z + 1) * HW);
#pragma unroll
            for (int k = 0; k < 8; k++) stg[k] = *(const float*)(nsrc + goffB[k]);
            if (k8) stg[8] = *(const float*)(nsrc + goffB[8]);
        }
        __syncthreads();   // A: raw ready; prior phase-3 hsq reads complete

        // phase 2: horizontal window sums (s, q) for A/B pixel pairs, all 46 rows
        for (int idx = tid; idx < 736; idx += 256) {
            int r = idx >> 4, xh = idx & 15;
            const float* rp = raw + r * 50 + 2 * xh;
            float v[16], w[16];
#pragma unroll
            for (int k = 0; k < 8; k++) {
                float2 p = *(const float2*)(rp + 2 * k);
                v[2 * k] = p.x; v[2 * k + 1] = p.y;
            }
#pragma unroll
            for (int k = 0; k < 16; k++) w[k] = v[k] * v[k];
            float ms = v[6] + v[7] + v[8] + v[9];
            float mq = w[6] + w[7] + w[8] + w[9];
            float sA5 = v[5] + ms, sB5 = ms + v[10];
            float qA5 = w[5] + mq, qB5 = mq + w[10];
            float sA9 = sA5 + v[3] + v[4] + v[10] + v[11];
            float sB9 = sB5 + v[4] + v[5] + v[11] + v[12];
            float qA9 = qA5 + w[3] + w[4] + w[10] + w[11];
            float qB9 = qB5 + w[4] + w[5] + w[11] + w[12];
            float sA15 = sA9 + v[0] + v[1] + v[2] + v[12] + v[13] + v[14];
            float sB15 = sB9 + v[1] + v[2] + v[3] + v[13] + v[14] + v[15];
            float qA15 = qA9 + w[0] + w[1] + w[2] + w[12] + w[13] + w[14];
            float qB15 = qB9 + w[1] + w[2] + w[3] + w[13] + w[14] + w[15];
            int base = r * 76 + 4 * xh;
            *(float4*)&hsq[0][base] = make_float4(sA5, qA5, sB5, qB5);
            *(float4*)&hsq[1][base] = make_float4(sA9, qA9, sB9, qB9);
            *(float4*)&hsq[2][base] = make_float4(sA15, qA15, sB15, qB15);
        }
        __syncthreads();   // B: hsq ready; all raw reads complete

        // phase 3: vertical sums (dual accumulators) + std finishing
#pragma unroll
        for (int wi = 0; wi < 3; wi++) {
            const int wlen = (wi == 0) ? 5 : ((wi == 1) ? 9 : 15);
            const int r0 = 2 * yp + 7 - (wlen >> 1);
            const float inv = 1.0f / (float)(wlen * wlen);
            const float ww = wwin[wi];
            const float* basep = &hsq[wi][4 * xq];
            float4 first = *(const float4*)(basep + r0 * 76);
            float4 e = first;
            float4 o = *(const float4*)(basep + (r0 + 1) * 76);
#pragma unroll
            for (int k = 2; k + 1 < wlen; k += 2) {
                float4 pe = *(const float4*)(basep + (r0 + k) * 76);
                float4 po = *(const float4*)(basep + (r0 + k + 1) * 76);
                e.x += pe.x; e.y += pe.y; e.z += pe.z; e.w += pe.w;
                o.x += po.x; o.y += po.y; o.z += po.z; o.w += po.w;
            }
            {   // last even row (wlen odd -> index wlen-1 is even)
                float4 pe = *(const float4*)(basep + (r0 + wlen - 1) * 76);
                e.x += pe.x; e.y += pe.y; e.z += pe.z; e.w += pe.w;
            }
            float4 accv = make_float4(e.x + o.x, e.y + o.y, e.z + o.z, e.w + o.w);
            float4 last = *(const float4*)(basep + (r0 + wlen) * 76);
            float sA1 = accv.x - first.x + last.x;
            float qA1 = accv.y - first.y + last.y;
            float sB1 = accv.z - first.z + last.z;
            float qB1 = accv.w - first.w + last.w;
            float mA0 = accv.x * inv, m2A0 = accv.y * inv;
            part[0] += ww * fast_sqrtf(fmaxf(m2A0 - mA0 * mA0, 0.f) + 1e-8f);
            float mB0 = accv.z * inv, m2B0 = accv.w * inv;
            part[1] += ww * fast_sqrtf(fmaxf(m2B0 - mB0 * mB0, 0.f) + 1e-8f);
            float mA1 = sA1 * inv, m2A1 = qA1 * inv;
            part[2] += ww * fast_sqrtf(fmaxf(m2A1 - mA1 * mA1, 0.f) + 1e-8f);
            float mB1 = sB1 * inv, m2B1 = qB1 * inv;
            part[3] += ww * fast_sqrtf(fmaxf(m2B1 - mB1 * mB1, 0.f) + 1e-8f);
        }
        // no barrier: next iter writes raw (disjoint from hsq); hsq rewritten only after next barrier A
    }

    // epilogue: fused value -> per-channel threshold + sigmoid, direct output write
    float fb0 = fb[0];
    int gy = by + 2 * yp, gx = bx + 2 * xq;
#pragma unroll
    for (int c = 0; c < 4; c++) {
        float lo = stats[(batch * 4 + c) * 2];
        float up = stats[(batch * 4 + c) * 2 + 1];
        float inv = 1.f / (up - lo);
        float v[4];
#pragma unroll
        for (int p = 0; p < 4; p++) {
            float ns = (part[p] + fb0 - lo) * inv;
            ns = fminf(fmaxf(ns, 0.f), 1.f);
            v[p] = 1.f / (1.f + fast_expf(3.f - 6.f * ns));
        }
        float* plane = out + ((size_t)(batch * 4 + c)) * HW;
        *(float2*)(plane + (size_t)gy * W + gx) = make_float2(v[0], v[1]);
        *(float2*)(plane + (size_t)(gy + 1) * W + gx) = make_float2(v[2], v[3]);
    }
}

extern "C" void kernel_launch(void* const* d_in, const int* in_sizes, int n_in,
                              void* d_out, int out_size, void* d_ws, size_t ws_size,
                              hipStream_t stream) {
    (void)in_sizes; (void)n_in; (void)out_size; (void)ws_size;
    const float* x = (const float*)d_in[0];
    const float* w1 = (const float*)d_in[1];
    const float* b1 = (const float*)d_in[2];
    const float* w2 = (const float*)d_in[3];
    const float* b2 = (const float*)d_in[4];
    const float* w3 = (const float*)d_in[5];
    const float* b3 = (const float*)d_in[6];
    const float* chw = (const float*)d_in[7];
    const float* fw = (const float*)d_in[8];
    const float* fb = (const float*)d_in[9];
    float* out = (float*)d_out;

    char* ws = (char*)d_ws;
    float* stats = (float*)ws;                         // 32 f
    double* part = (double*)(ws + 256);                // 1024 d, ends 8448
    _Float16* w1a = (_Float16*)(ws + 8448);            // 2048 f16, ends 12544
    _Float16* w3f = (_Float16*)(ws + 24832);           // 3072 f16, ends 30976
    _Float16* w2bh = (_Float16*)(ws + 37120);          // 4608 f16, ends 46336
    float* f3all = (float*)(ws + 65536);               // 4 batches x 8 ch x HW f32 = 128 MB
    _Float16* f2n = (_Float16*)(ws + 134283264);       // 32 MB h-only (reused per batch)

    stats_partial<<<512, 256, 0, stream>>>(x, part);
    stats_final_prep<<<1, 256, 0, stream>>>(part, chw, w1, w2, w3, stats, w1a, w3f, w2bh);

    for (int b = 0; b < 4; b++) {
        const float* xb = x + (size_t)b * 4 * HW;
        conv12_mfma<<<dim3(32, 128), 256, 0, stream>>>(xb, w1a, b1, w2bh, b2, f2n);
        conv3_mfma<<<dim3(32, 128), 256, 0, stream>>>(f2n, w3f, b3, f3all + (size_t)b * 8 * HW);
    }
    stdfuse_fused<<<dim3(32, 32, 4), 256, 0, stream>>>(f3all, fw, fb, stats, out);
}

// Round 8
// 399.789 us; speedup vs baseline: 1.2988x; 1.0633x over previous
//
#include <hip/hip_runtime.h>
#include <math.h>

#define H 1024
#define W 1024
#define HW (H * W)

typedef _Float16 half8 __attribute__((ext_vector_type(8)));
typedef _Float16 half4 __attribute__((ext_vector_type(4)));
typedef float f32x4 __attribute__((ext_vector_type(4)));
typedef unsigned uint4v __attribute__((ext_vector_type(4)));

__device__ __forceinline__ float fast_sqrtf(float x) { return __builtin_amdgcn_sqrtf(x); }
__device__ __forceinline__ float fast_expf(float x) { return __builtin_amdgcn_exp2f(x * 1.44269504088896340736f); }

union U16 { unsigned short u; _Float16 f; };

// assemble half8 of the low-16 halves of 8 packed u32 via v_perm_b32
__device__ __forceinline__ half8 unpack_lo8(const unsigned* u) {
    uint4v a;
    a.x = __builtin_amdgcn_perm(u[1], u[0], 0x05040100);
    a.y = __builtin_amdgcn_perm(u[3], u[2], 0x05040100);
    a.z = __builtin_amdgcn_perm(u[5], u[4], 0x05040100);
    a.w = __builtin_amdgcn_perm(u[7], u[6], 0x05040100);
    return __builtin_bit_cast(half8, a);
}
__device__ __forceinline__ half8 unpack_lo4(const unsigned* u) {
    uint4v a;
    a.x = __builtin_amdgcn_perm(u[1], u[0], 0x05040100);
    a.y = __builtin_amdgcn_perm(u[3], u[2], 0x05040100);
    a.z = 0; a.w = 0;
    return __builtin_bit_cast(half8, a);
}

// ---------------- stats pass 1: partial sum/sumsq per (b,c) chunk ----------------
__global__ __launch_bounds__(256) void stats_partial(const float* __restrict__ x,
                                                     double* __restrict__ part) {
    int blk = blockIdx.x;
    int bc = blk >> 5;
    int j = blk & 31;
    const float* p = x + (size_t)bc * HW + (size_t)j * (HW / 32);
    int tid = threadIdx.x;
    double s = 0.0, q = 0.0;
    const float4* p4 = (const float4*)p;
    for (int i = tid; i < (HW / 32) / 4; i += 256) {
        float4 v = p4[i];
        s += (double)v.x + (double)v.y + (double)v.z + (double)v.w;
        q += (double)v.x * v.x + (double)v.y * v.y + (double)v.z * v.z + (double)v.w * v.w;
    }
    __shared__ double ls[256], lq[256];
    ls[tid] = s;
    lq[tid] = q;
    __syncthreads();
    for (int ofs = 128; ofs > 0; ofs >>= 1) {
        if (tid < ofs) { ls[tid] += ls[tid + ofs]; lq[tid] += lq[tid + ofs]; }
        __syncthreads();
    }
    if (tid == 0) {
        part[blk * 2] = ls[0];
        part[blk * 2 + 1] = lq[0];
    }
}

// ---------------- stats pass 2 + weight prep (h-only conv weights) ----------------
__global__ __launch_bounds__(256) void stats_final_prep(const double* __restrict__ part,
                                                        const float* __restrict__ chw,
                                                        const float* __restrict__ w1,
                                                        const float* __restrict__ w2,
                                                        const float* __restrict__ w3,
                                                        float* __restrict__ stats,
                                                        _Float16* __restrict__ w1a,
                                                        _Float16* __restrict__ w3f,
                                                        _Float16* __restrict__ w2bh) {
    int tid = threadIdx.x;
    __shared__ float cw[4];
    if (tid == 0) {
        float m = fmaxf(fmaxf(chw[0], chw[1]), fmaxf(chw[2], chw[3]));
        float e0 = expf(chw[0] - m), e1 = expf(chw[1] - m);
        float e2 = expf(chw[2] - m), e3 = expf(chw[3] - m);
        float s = e0 + e1 + e2 + e3;
        cw[0] = e0 / s; cw[1] = e1 / s; cw[2] = e2 / s; cw[3] = e3 / s;
    }
    __syncthreads();
    if (tid < 16) {
        double s = 0.0, q = 0.0;
        for (int j = 0; j < 32; j++) {
            s += part[(tid * 32 + j) * 2];
            q += part[(tid * 32 + j) * 2 + 1];
        }
        double n = (double)HW;
        double var = (q - s * s / n) / (n - 1.0);
        if (var < 0) var = 0;
        float gs = (float)sqrt(var);
        int c = tid & 3;
        float gf = fminf(fmaxf(gs * 5.0f, 0.5f), 2.0f);
        float cf = fminf(fmaxf(gs * cw[c] * 2.0f, 0.8f), 1.2f);
        stats[tid * 2] = 0.05f * gf * cf;
        stats[tid * 2 + 1] = 0.20f * gf * cf;
    }
    // conv1 A-frags, h-only: 4 sets (c,h) of 64 lanes x 8
    for (int i = tid; i < 256; i += 256) {
        int s = i >> 6, l = i & 63;
        int c = s >> 1, h = s & 1;
        int m = l & 15, cg = l >> 4;
        int co = h * 16 + m;
#pragma unroll
        for (int j = 0; j < 8; j++) {
            int k = c * 32 + cg * 8 + j;
            float v = 0.f;
            if (k < 36) {
                int t = k >> 2, ci = k & 3;
                v = w1[(co * 4 + ci) * 9 + t];
            }
            w1a[i * 8 + j] = (_Float16)v;
        }
    }
    for (int idx = tid; idx < 576; idx += 256) {           // conv2 B-frags (h only)
        int t = idx >> 6, l = idx & 63;
        int co = l & 15, cg = l >> 4;
#pragma unroll
        for (int j = 0; j < 8; j++) {
            int ci = cg * 8 + j;
            w2bh[idx * 8 + j] = (_Float16)w2[(co * 32 + ci) * 9 + t];
        }
    }
    for (int idx = tid; idx < 384; idx += 256) {           // conv3 B-frags: 6 sets (ky,grp) h-only
        int t = idx >> 6, l = idx & 63;
        int ky = t / 2, grp = t & 1;
        int co = l & 15, bq = l >> 4;
#pragma unroll
        for (int j = 0; j < 8; j++) {
            int k = bq * 8 + j;
            float v = 0.f;
            if (co < 8) {
                if (grp == 0) {
                    int kxp = k >> 4, ci = k & 15;
                    v = w3[((co * 16 + ci) * 3 + ky) * 3 + kxp];
                } else if (k < 16) {
                    v = w3[((co * 16 + k) * 3 + ky) * 3 + 2];
                }
            }
            w3f[idx * 8 + j] = (_Float16)v;
        }
    }
}

// ---------------- fused conv1+conv2, f16 h-only MFMA ----------------
__global__ __launch_bounds__(256, 4) void conv12_mfma(const float* __restrict__ x,
                                                      const _Float16* __restrict__ w1a,
                                                      const float* __restrict__ b1,
                                                      const _Float16* __restrict__ wbh,
                                                      const float* __restrict__ b2,
                                                      _Float16* __restrict__ f2n,
                                                      size_t f2n_bstride, int batch0) {
    __shared__ __align__(16) char smem[34112];
    char* f1t = smem;                                  // 10*34*80 = 27200 B (h-only)
    unsigned* xhl = (unsigned*)(smem + 27200);         // [4][12][36] u32 (f16 h in low16)
    int tid = threadIdx.x;
    int lane = tid & 63;
    int wid = tid >> 6;
    int bx = blockIdx.x * 32, by = blockIdx.y * 8;
    int n = lane & 15, cg = lane >> 4;
    int m = lane & 15, b = lane >> 4;
    const float* xb = x + (size_t)(batch0 + blockIdx.z) * 4 * HW;
    _Float16* f2nb = f2n + (size_t)blockIdx.z * f2n_bstride;

    // phase 1: stage x halo (rows by-2..by+9, cols bx-2..bx+33) as f16 (low half of u32)
    {
        int idx = tid;
        int r = tid / 36, c = tid - r * 36, ci = 0;
#pragma unroll
        for (int it = 0; it < 7; ++it) {
            if (idx < 1728) {
                int gy = by + r - 2, gx = bx + c - 2;
                float v = 0.f;
                if ((unsigned)gy < H && (unsigned)gx < W) v = xb[ci * HW + gy * W + gx];
                U16 a; a.f = (_Float16)v;
                xhl[idx] = (unsigned)a.u;
            }
            idx += 256;
            c += 4; if (c >= 36) { c -= 36; r += 1; }
            r += 7; if (r >= 12) { r -= 12; ci += 1; }
        }
    }

    half8 Wf00 = *(const half8*)(w1a + (0 * 64 + lane) * 8);
    half8 Wf01 = *(const half8*)(w1a + (1 * 64 + lane) * 8);
    half8 Wf10 = *(const half8*)(w1a + (2 * 64 + lane) * 8);
    half8 Wf11 = *(const half8*)(w1a + (3 * 64 + lane) * 8);
    float bias1[8];
#pragma unroll
    for (int h = 0; h < 2; h++)
#pragma unroll
        for (int j = 0; j < 4; j++)
            bias1[h * 4 + j] = b1[h * 16 + cg * 4 + j];
    half8 Bh[9];
#pragma unroll
    for (int t = 0; t < 9; t++)
        Bh[t] = *(const half8*)(wbh + (t * 64 + lane) * 8);
    f32x4 binit;
#pragma unroll
    for (int j = 0; j < 4; j++) binit[j] = b2[b * 4 + j];

    int t0 = 2 * cg, t1 = 2 * cg + 1;
    int dy0 = (t0 * 11) >> 5, dx0 = t0 - 3 * dy0;
    int dy1 = (t1 * 11) >> 5, dx1 = t1 - 3 * dy1;
    int off0 = dy0 * 36 + dx0, off1 = dy1 * 36 + dx1;
    __syncthreads();

    // phase 2: conv1 via MFMA; 22 tiles of 16 px cover the 340-px halo
#pragma unroll 1
    for (int tt = wid; tt < 22; tt += 4) {
        int p = tt * 16 + n;
        bool valid = p < 340;
        int pc = valid ? p : 339;
        int ry = pc / 34, cx = pc - ry * 34;
        int gy = by + ry - 1, gx = bx + cx - 1;
        bool ok = ((unsigned)gy < H) && ((unsigned)gx < W);
        int base = ry * 36 + cx;
        unsigned u0[8];
#pragma unroll
        for (int j = 0; j < 8; j++)
            u0[j] = xhl[(j & 3) * 432 + base + ((j < 4) ? off0 : off1)];
        half8 Xh0 = unpack_lo8(u0);
        half8 Xh1 = {0, 0, 0, 0, 0, 0, 0, 0};
        if (cg == 0) {
            unsigned u1[4];
#pragma unroll
            for (int j = 0; j < 4; j++)
                u1[j] = xhl[j * 432 + base + 74];       // tap 8 (dy=2,dx=2)
            Xh1 = unpack_lo4(u1);
        }
        f32x4 d0, d1;
#pragma unroll
        for (int j = 0; j < 4; j++) { d0[j] = bias1[j]; d1[j] = bias1[4 + j]; }
        d0 = __builtin_amdgcn_mfma_f32_16x16x32_f16(Wf00, Xh0, d0, 0, 0, 0);
        d0 = __builtin_amdgcn_mfma_f32_16x16x32_f16(Wf10, Xh1, d0, 0, 0, 0);
        d1 = __builtin_amdgcn_mfma_f32_16x16x32_f16(Wf01, Xh0, d1, 0, 0, 0);
        d1 = __builtin_amdgcn_mfma_f32_16x16x32_f16(Wf11, Xh1, d1, 0, 0, 0);
        if (valid) {
            char* pxb = f1t + ry * 2720 + cx * 80;
#pragma unroll
            for (int h = 0; h < 2; h++) {
                f32x4 d = h ? d1 : d0;
                half4 hq;
#pragma unroll
                for (int j = 0; j < 4; j++) {
                    float v = d[j];
                    v = fmaxf(v, 0.2f * v);
                    v = ok ? v : 0.f;
                    hq[j] = (_Float16)v;
                }
                *(half4*)(pxb + (h * 4 + cg) * 8) = hq;
            }
        }
    }
    __syncthreads();

    // phase 3: conv2 via rolling-row f16 MFMA, D = W*X (lane owns px, 4 co)
    int wx = wid & 1, wy = wid >> 1;
    f32x4 acc2[4];
#pragma unroll
    for (int r = 0; r < 4; r++) acc2[r] = binit;
#pragma unroll
    for (int iy = 0; iy < 6; iy++) {
        int f1row = wy * 4 + iy;
        half8 ah[3];
#pragma unroll
        for (int kx = 0; kx < 3; kx++) {
            int pxi = wx * 16 + m + kx;
            ah[kx] = *(const half8*)(f1t + f1row * 2720 + pxi * 80 + b * 16);
        }
#pragma unroll
        for (int kx = 0; kx < 3; kx++) {
#pragma unroll
            for (int ry = 0; ry < 4; ry++) {
                if (ry >= iy - 2 && ry <= iy) {
                    const int t = (iy - ry) * 3 + kx;
                    acc2[ry] = __builtin_amdgcn_mfma_f32_16x16x32_f16(Bh[t], ah[kx], acc2[ry], 0, 0, 0);
                }
            }
        }
    }

    // epilogue (h-only f2n): leaky -> f16 -> direct store, 32B/px
    int x0 = bx + wx * 16 + m;
    int y0 = by + wy * 4;
    int co_off = b * 4;
#pragma unroll
    for (int ry = 0; ry < 4; ry++) {
        half4 hq;
#pragma unroll
        for (int j = 0; j < 4; j++) {
            float v = acc2[ry][j];
            v = fmaxf(v, 0.2f * v);
            hq[j] = (_Float16)v;
        }
        *(half4*)(f2nb + ((size_t)(y0 + ry) * W + x0) * 16 + co_off) = hq;
    }
}

// ---------------- conv3: h-only f16 MFMA, 32x8 tile ----------------
__global__ __launch_bounds__(256) void conv3_mfma(const _Float16* __restrict__ f2n,
                                                  size_t f2n_bstride, int batch0,
                                                  const _Float16* __restrict__ w3f,
                                                  const float* __restrict__ bias,
                                                  float* __restrict__ f3all) {
    __shared__ __align__(16) char st[10 * 34 * 40];    // 13600 B
    int tid = threadIdx.x;
    int lane = tid & 63;
    int wid = tid >> 6;
    int bx = blockIdx.x * 32, by = blockIdx.y * 8;
    const _Float16* f2nb = f2n + (size_t)blockIdx.z * f2n_bstride;
    float* f3 = f3all + (size_t)(batch0 + blockIdx.z) * 8 * HW;

    // stage: rows by-1..by+8, px bx-1..bx+32, 2 x 16B chunks per px (680 tasks)
    for (int idx = tid; idx < 680; idx += 256) {
        int c0 = idx & 1;
        int rp = idx >> 1;
        int r = rp / 34, p = rp - r * 34;
        int gy = by + r - 1, gx = bx + p - 1;
        half8 v = {0, 0, 0, 0, 0, 0, 0, 0};
        if ((unsigned)gy < H && (unsigned)gx < W)
            v = *(const half8*)(f2nb + ((size_t)gy * W + gx) * 16 + c0 * 8);
        *(half8*)(st + r * 1360 + p * 40 + c0 * 16) = v;
    }

    half8 F0[3], F1[3];                                // per ky: grp0-h, grp1-h
#pragma unroll
    for (int ky = 0; ky < 3; ky++) {
        F0[ky] = *(const half8*)(w3f + ((ky * 2 + 0) * 64 + lane) * 8);
        F1[ky] = *(const half8*)(w3f + ((ky * 2 + 1) * 64 + lane) * 8);
    }
    int m = lane & 15, b = lane >> 4;
    int halfco = b & 1, kxp = b >> 1;
    int wx = wid & 1, wy = wid >> 1;
    float bc = (m < 8) ? bias[m] : 0.f;
    f32x4 acc[4];
#pragma unroll
    for (int r = 0; r < 4; r++) acc[r] = (f32x4){bc, bc, bc, bc};
    int pA = wx * 16 + m + kxp;                        // halo-local px for A (kx -1,0)
    int pB = wx * 16 + m + 2;                          // halo-local px for B (kx +1)
    __syncthreads();

#pragma unroll
    for (int iy = 0; iy < 6; iy++) {
        const char* rp = st + (wy * 4 + iy) * 1360;
        half8 ka_h = *(const half8*)(rp + pA * 40 + halfco * 16);
        half8 kb_h = *(const half8*)(rp + pB * 40 + halfco * 16);
#pragma unroll
        for (int ry = 0; ry < 4; ry++) {
            if (ry >= iy - 2 && ry <= iy) {
                const int ky = iy - ry;
                acc[ry] = __builtin_amdgcn_mfma_f32_16x16x32_f16(ka_h, F0[ky], acc[ry], 0, 0, 0);
                acc[ry] = __builtin_amdgcn_mfma_f32_16x16x32_f16(kb_h, F1[ky], acc[ry], 0, 0, 0);
            }
        }
    }

    if (m < 8) {
#pragma unroll
        for (int ry = 0; ry < 4; ry++) {
            int y = by + wy * 4 + ry;
            *(float4*)(f3 + (size_t)m * HW + (size_t)y * W + bx + wx * 16 + b * 4) =
                make_float4(acc[ry][0], acc[ry][1], acc[ry][2], acc[ry][3]);
        }
    }
}

// ---------------- stdfuse v5: packed-f16 hsq (LDS 28.4 KB -> 5 blocks/CU) ----------------
// hsq stored as half4 {sA,sB,qA,qB}; vertical sums accumulate in packed f16 (v_pk_add_f16).
// Row stride 68 halfs (136 B) staggers the 4 yp-groups across banks.
__global__ __launch_bounds__(256) void stdfuse_fused(const float* __restrict__ f3all,
                                                     const float* __restrict__ fw,
                                                     const float* __restrict__ fb,
                                                     const float* __restrict__ stats,
                                                     float* __restrict__ out) {
    __shared__ __align__(16) float raw[46 * 50];
    __shared__ __align__(16) _Float16 hsqh[3][46 * 68];
    __shared__ int rowOff[46];      // reflected gy * W (element offset)
    __shared__ int gxcol[46];       // reflected gx
    int tid = threadIdx.x;
    int xq = tid & 15, yp = tid >> 4;
    int bx = blockIdx.x * 32, by = blockIdx.y * 32;
    int batch = blockIdx.z;
    const float* f3 = f3all + (size_t)batch * 8 * HW;

    if (tid < 46) {
        int gy = by + tid - 7;
        gy = gy < 0 ? -gy : (gy > 1023 ? 2046 - gy : gy);
        rowOff[tid] = gy * W;
        int gx = bx + tid - 7;
        gx = gx < 0 ? -gx : (gx > 1023 ? 2046 - gx : gx);
        gxcol[tid] = gx;
    }
    __syncthreads();

    // per-thread staging task table (channel-invariant): 2116 = 8*256 + 68 tasks
    int goffB[9];   // global byte offset within a channel plane
    int laddB[9];   // LDS byte offset into raw
    const bool k8 = tid < 68;
#pragma unroll
    for (int k = 0; k < 9; k++) {
        int idx = tid + k * 256;
        int idc = idx < 2116 ? idx : 2115;
        int r = idc / 46, c = idc - r * 46;
        goffB[k] = (rowOff[r] + gxcol[c]) * 4;
        laddB[k] = (r * 50 + c) * 4;
    }

    float wwin[3] = {fw[0] * 0.125f, fw[1] * 0.125f, fw[2] * 0.125f};
    float part[4] = {0.f, 0.f, 0.f, 0.f};

    // prologue: load channel 0 into registers
    float stg[9];
    {
        const char* src = (const char*)f3;
#pragma unroll
        for (int k = 0; k < 8; k++) stg[k] = *(const float*)(src + goffB[k]);
        stg[8] = k8 ? *(const float*)(src + goffB[8]) : 0.f;
    }

    for (int z = 0; z < 8; z++) {
        // write staged registers to raw (safe: prior phase-2 raw reads ended at barrier B)
        char* rb = (char*)raw;
#pragma unroll
        for (int k = 0; k < 8; k++) *(float*)(rb + laddB[k]) = stg[k];
        if (k8) *(float*)(rb + laddB[8]) = stg[8];

        // T14: issue next channel's loads BEFORE the barrier; latency hides under phase 2+3
        if (z < 7) {
            const char* nsrc = (const char*)(f3 + (size_t)(z + 1) * HW);
#pragma unroll
            for (int k = 0; k < 8; k++) stg[k] = *(const float*)(nsrc + goffB[k]);
            if (k8) stg[8] = *(const float*)(nsrc + goffB[8]);
        }
        __syncthreads();   // A: raw ready; prior phase-3 hsqh reads complete

        // phase 2: horizontal window sums (f32) -> packed f16 {sA,sB,qA,qB} per window
        for (int idx = tid; idx < 736; idx += 256) {
            int r = idx >> 4, xh = idx & 15;
            const float* rp = raw + r * 50 + 2 * xh;
            float v[16], w[16];
#pragma unroll
            for (int k = 0; k < 8; k++) {
                float2 p = *(const float2*)(rp + 2 * k);
                v[2 * k] = p.x; v[2 * k + 1] = p.y;
            }
#pragma unroll
            for (int k = 0; k < 16; k++) w[k] = v[k] * v[k];
            float ms = v[6] + v[7] + v[8] + v[9];
            float mq = w[6] + w[7] + w[8] + w[9];
            float sA5 = v[5] + ms, sB5 = ms + v[10];
            float qA5 = w[5] + mq, qB5 = mq + w[10];
            float sA9 = sA5 + v[3] + v[4] + v[10] + v[11];
            float sB9 = sB5 + v[4] + v[5] + v[11] + v[12];
            float qA9 = qA5 + w[3] + w[4] + w[10] + w[11];
            float qB9 = qB5 + w[4] + w[5] + w[11] + w[12];
            float sA15 = sA9 + v[0] + v[1] + v[2] + v[12] + v[13] + v[14];
            float sB15 = sB9 + v[1] + v[2] + v[3] + v[13] + v[14] + v[15];
            float qA15 = qA9 + w[0] + w[1] + w[2] + w[12] + w[13] + w[14];
            float qB15 = qB9 + w[1] + w[2] + w[3] + w[13] + w[14] + w[15];
            int ho = r * 68 + 4 * xh;
            *(half4*)&hsqh[0][ho] = (half4){(_Float16)sA5,  (_Float16)sB5,  (_Float16)qA5,  (_Float16)qB5};
            *(half4*)&hsqh[1][ho] = (half4){(_Float16)sA9,  (_Float16)sB9,  (_Float16)qA9,  (_Float16)qB9};
            *(half4*)&hsqh[2][ho] = (half4){(_Float16)sA15, (_Float16)sB15, (_Float16)qA15, (_Float16)qB15};
        }
        __syncthreads();   // B: hsqh ready; all raw reads complete

        // phase 3: vertical sums in packed f16 (dual accumulators) + f32 finishing
#pragma unroll
        for (int wi = 0; wi < 3; wi++) {
            const int wlen = (wi == 0) ? 5 : ((wi == 1) ? 9 : 15);
            const int r0 = 2 * yp + 7 - (wlen >> 1);
            const float inv = 1.0f / (float)(wlen * wlen);
            const float ww = wwin[wi];
            const _Float16* basep = &hsqh[wi][4 * xq];
            half4 first = *(const half4*)(basep + r0 * 68);
            half4 e = first;
            half4 o = *(const half4*)(basep + (r0 + 1) * 68);
#pragma unroll
            for (int k = 2; k + 1 < wlen; k += 2) {
                e += *(const half4*)(basep + (r0 + k) * 68);
                o += *(const half4*)(basep + (r0 + k + 1) * 68);
            }
            e += *(const half4*)(basep + (r0 + wlen - 1) * 68);   // last even row
            half4 tot = e + o;
            half4 last = *(const half4*)(basep + (r0 + wlen) * 68);
            half4 sh = tot - first + last;
            float sA0 = (float)tot[0], sB0 = (float)tot[1];
            float qA0 = (float)tot[2], qB0 = (float)tot[3];
            float sA1 = (float)sh[0],  sB1 = (float)sh[1];
            float qA1 = (float)sh[2],  qB1 = (float)sh[3];
            float mA0 = sA0 * inv, m2A0 = qA0 * inv;
            part[0] += ww * fast_sqrtf(fmaxf(m2A0 - mA0 * mA0, 0.f) + 1e-8f);
            float mB0 = sB0 * inv, m2B0 = qB0 * inv;
            part[1] += ww * fast_sqrtf(fmaxf(m2B0 - mB0 * mB0, 0.f) + 1e-8f);
            float mA1 = sA1 * inv, m2A1 = qA1 * inv;
            part[2] += ww * fast_sqrtf(fmaxf(m2A1 - mA1 * mA1, 0.f) + 1e-8f);
            float mB1 = sB1 * inv, m2B1 = qB1 * inv;
            part[3] += ww * fast_sqrtf(fmaxf(m2B1 - mB1 * mB1, 0.f) + 1e-8f);
        }
        // no barrier: next iter writes raw (disjoint from hsqh); hsqh rewritten only after next barrier A
    }

    // epilogue: fused value -> per-channel threshold + sigmoid, direct output write
    float fb0 = fb[0];
    int gy = by + 2 * yp, gx = bx + 2 * xq;
#pragma unroll
    for (int c = 0; c < 4; c++) {
        float lo = stats[(batch * 4 + c) * 2];
        float up = stats[(batch * 4 + c) * 2 + 1];
        float inv = 1.f / (up - lo);
        float v[4];
#pragma unroll
        for (int p = 0; p < 4; p++) {
            float ns = (part[p] + fb0 - lo) * inv;
            ns = fminf(fmaxf(ns, 0.f), 1.f);
            v[p] = 1.f / (1.f + fast_expf(3.f - 6.f * ns));
        }
        float* plane = out + ((size_t)(batch * 4 + c)) * HW;
        *(float2*)(plane + (size_t)gy * W + gx) = make_float2(v[0], v[1]);
        *(float2*)(plane + (size_t)(gy + 1) * W + gx) = make_float2(v[2], v[3]);
    }
}

extern "C" void kernel_launch(void* const* d_in, const int* in_sizes, int n_in,
                              void* d_out, int out_size, void* d_ws, size_t ws_size,
                              hipStream_t stream) {
    (void)in_sizes; (void)n_in; (void)out_size;
    const float* x = (const float*)d_in[0];
    const float* w1 = (const float*)d_in[1];
    const float* b1 = (const float*)d_in[2];
    const float* w2 = (const float*)d_in[3];
    const float* b2 = (const float*)d_in[4];
    const float* w3 = (const float*)d_in[5];
    const float* b3 = (const float*)d_in[6];
    const float* chw = (const float*)d_in[7];
    const float* fw = (const float*)d_in[8];
    const float* fb = (const float*)d_in[9];
    float* out = (float*)d_out;

    char* ws = (char*)d_ws;
    float* stats = (float*)ws;                         // 32 f
    double* part = (double*)(ws + 256);                // 1024 d, ends 8448
    _Float16* w1a = (_Float16*)(ws + 8448);            // 2048 f16, ends 12544
    _Float16* w3f = (_Float16*)(ws + 24832);           // 3072 f16, ends 30976
    _Float16* w2bh = (_Float16*)(ws + 37120);          // 4608 f16, ends 46336
    float* f3all = (float*)(ws + 65536);               // 4 batches x 8 ch x HW f32 = 128 MB
    _Float16* f2n = (_Float16*)(ws + 134283264);       // h-only planes of 32 MB

    // wide mode: 4 f2n planes -> single conv12 + single conv3 dispatch (needs 256.06 MB ws)
    const size_t PLANE = (size_t)16 * HW;              // f16 elements per f2n plane
    const size_t WIDE_WS = 134283264ULL + 4ULL * PLANE * sizeof(_Float16);
    bool wide = ws_size >= WIDE_WS;

    stats_partial<<<512, 256, 0, stream>>>(x, part);
    stats_final_prep<<<1, 256, 0, stream>>>(part, chw, w1, w2, w3, stats, w1a, w3f, w2bh);

    if (wide) {
        conv12_mfma<<<dim3(32, 128, 4), 256, 0, stream>>>(x, w1a, b1, w2bh, b2, f2n, PLANE, 0);
        conv3_mfma<<<dim3(32, 128, 4), 256, 0, stream>>>(f2n, PLANE, 0, w3f, b3, f3all);
    } else {
        for (int b = 0; b < 4; b++) {
            conv12_mfma<<<dim3(32, 128, 1), 256, 0, stream>>>(x, w1a, b1, w2bh, b2, f2n, 0, b);
            conv3_mfma<<<dim3(32, 128, 1), 256, 0, stream>>>(f2n, 0, b, w3f, b3, f3all);
        }
    }
    stdfuse_fused<<<dim3(32, 32, 4), 256, 0, stream>>>(f3all, fw, fb, stats, out);
}

// Round 10
// 355.975 us; speedup vs baseline: 1.4586x; 1.1231x over previous
//
#include <hip/hip_runtime.h>
#include <math.h>

#define H 1024
#define W 1024
#define HW (H * W)

typedef _Float16 half8 __attribute__((ext_vector_type(8)));
typedef _Float16 half4 __attribute__((ext_vector_type(4)));
typedef _Float16 h2 __attribute__((ext_vector_type(2)));
typedef float f32x4 __attribute__((ext_vector_type(4)));

__device__ __forceinline__ float fast_sqrtf(float x) { return __builtin_amdgcn_sqrtf(x); }
__device__ __forceinline__ float fast_expf(float x) { return __builtin_amdgcn_exp2f(x * 1.44269504088896340736f); }

__device__ __forceinline__ h2 pkrtz(float a, float b) {
    return __builtin_bit_cast(h2, __builtin_amdgcn_cvt_pkrtz(a, b));
}

// convert 8 staged f32 bit-patterns to half8 via v_cvt_pkrtz_f16_f32 (RTZ; headroom-safe)
__device__ __forceinline__ half8 cvt8(const unsigned* u) {
    h2 p0 = pkrtz(__builtin_bit_cast(float, u[0]), __builtin_bit_cast(float, u[1]));
    h2 p1 = pkrtz(__builtin_bit_cast(float, u[2]), __builtin_bit_cast(float, u[3]));
    h2 p2 = pkrtz(__builtin_bit_cast(float, u[4]), __builtin_bit_cast(float, u[5]));
    h2 p3 = pkrtz(__builtin_bit_cast(float, u[6]), __builtin_bit_cast(float, u[7]));
    half8 r;
    r[0] = p0[0]; r[1] = p0[1]; r[2] = p1[0]; r[3] = p1[1];
    r[4] = p2[0]; r[5] = p2[1]; r[6] = p3[0]; r[7] = p3[1];
    return r;
}
__device__ __forceinline__ half8 cvt4(const unsigned* u) {
    h2 p0 = pkrtz(__builtin_bit_cast(float, u[0]), __builtin_bit_cast(float, u[1]));
    h2 p1 = pkrtz(__builtin_bit_cast(float, u[2]), __builtin_bit_cast(float, u[3]));
    half8 r = {0, 0, 0, 0, 0, 0, 0, 0};
    r[0] = p0[0]; r[1] = p0[1]; r[2] = p1[0]; r[3] = p1[1];
    return r;
}

// ---------------- stats pass 1: partial sum/sumsq per (b,c) chunk ----------------
__global__ __launch_bounds__(256) void stats_partial(const float* __restrict__ x,
                                                     double* __restrict__ part) {
    int blk = blockIdx.x;
    int bc = blk >> 5;
    int j = blk & 31;
    const float* p = x + (size_t)bc * HW + (size_t)j * (HW / 32);
    int tid = threadIdx.x;
    double s = 0.0, q = 0.0;
    const float4* p4 = (const float4*)p;
    for (int i = tid; i < (HW / 32) / 4; i += 256) {
        float4 v = p4[i];
        s += (double)v.x + (double)v.y + (double)v.z + (double)v.w;
        q += (double)v.x * v.x + (double)v.y * v.y + (double)v.z * v.z + (double)v.w * v.w;
    }
    __shared__ double ls[256], lq[256];
    ls[tid] = s;
    lq[tid] = q;
    __syncthreads();
    for (int ofs = 128; ofs > 0; ofs >>= 1) {
        if (tid < ofs) { ls[tid] += ls[tid + ofs]; lq[tid] += lq[tid + ofs]; }
        __syncthreads();
    }
    if (tid == 0) {
        part[blk * 2] = ls[0];
        part[blk * 2 + 1] = lq[0];
    }
}

// ---------------- stats pass 2 + weight prep (h-only conv weights) ----------------
__global__ __launch_bounds__(256) void stats_final_prep(const double* __restrict__ part,
                                                        const float* __restrict__ chw,
                                                        const float* __restrict__ w1,
                                                        const float* __restrict__ w2,
                                                        const float* __restrict__ w3,
                                                        float* __restrict__ stats,
                                                        _Float16* __restrict__ w1a,
                                                        _Float16* __restrict__ w3f,
                                                        _Float16* __restrict__ w2bh) {
    int tid = threadIdx.x;
    __shared__ float cw[4];
    if (tid == 0) {
        float m = fmaxf(fmaxf(chw[0], chw[1]), fmaxf(chw[2], chw[3]));
        float e0 = expf(chw[0] - m), e1 = expf(chw[1] - m);
        float e2 = expf(chw[2] - m), e3 = expf(chw[3] - m);
        float s = e0 + e1 + e2 + e3;
        cw[0] = e0 / s; cw[1] = e1 / s; cw[2] = e2 / s; cw[3] = e3 / s;
    }
    __syncthreads();
    if (tid < 16) {
        double s = 0.0, q = 0.0;
        for (int j = 0; j < 32; j++) {
            s += part[(tid * 32 + j) * 2];
            q += part[(tid * 32 + j) * 2 + 1];
        }
        double n = (double)HW;
        double var = (q - s * s / n) / (n - 1.0);
        if (var < 0) var = 0;
        float gs = (float)sqrt(var);
        int c = tid & 3;
        float gf = fminf(fmaxf(gs * 5.0f, 0.5f), 2.0f);
        float cf = fminf(fmaxf(gs * cw[c] * 2.0f, 0.8f), 1.2f);
        stats[tid * 2] = 0.05f * gf * cf;
        stats[tid * 2 + 1] = 0.20f * gf * cf;
    }
    // conv1 A-frags, h-only: 4 sets (c,h) of 64 lanes x 8
    for (int i = tid; i < 256; i += 256) {
        int s = i >> 6, l = i & 63;
        int c = s >> 1, h = s & 1;
        int m = l & 15, cg = l >> 4;
        int co = h * 16 + m;
#pragma unroll
        for (int j = 0; j < 8; j++) {
            int k = c * 32 + cg * 8 + j;
            float v = 0.f;
            if (k < 36) {
                int t = k >> 2, ci = k & 3;
                v = w1[(co * 4 + ci) * 9 + t];
            }
            w1a[i * 8 + j] = (_Float16)v;
        }
    }
    for (int idx = tid; idx < 576; idx += 256) {           // conv2 B-frags (h only)
        int t = idx >> 6, l = idx & 63;
        int co = l & 15, cg = l >> 4;
#pragma unroll
        for (int j = 0; j < 8; j++) {
            int ci = cg * 8 + j;
            w2bh[idx * 8 + j] = (_Float16)w2[(co * 32 + ci) * 9 + t];
        }
    }
    for (int idx = tid; idx < 384; idx += 256) {           // conv3 B-frags: 6 sets (ky,grp) h-only
        int t = idx >> 6, l = idx & 63;
        int ky = t / 2, grp = t & 1;
        int co = l & 15, bq = l >> 4;
#pragma unroll
        for (int j = 0; j < 8; j++) {
            int k = bq * 8 + j;
            float v = 0.f;
            if (co < 8) {
                if (grp == 0) {
                    int kxp = k >> 4, ci = k & 15;
                    v = w3[((co * 16 + ci) * 3 + ky) * 3 + kxp];
                } else if (k < 16) {
                    v = w3[((co * 16 + k) * 3 + ky) * 3 + 2];
                }
            }
            w3f[idx * 8 + j] = (_Float16)v;
        }
    }
}

// ---------------- fused conv1+conv2, f16 h-only MFMA ----------------
// v9: xhl staged as raw f32 bits (no staging cvt); f16 conversion fused into unpack
// via v_cvt_pkrtz. Multi-batch via blockIdx.z.
__global__ __launch_bounds__(256, 4) void conv12_mfma(const float* __restrict__ x,
                                                      const _Float16* __restrict__ w1a,
                                                      const float* __restrict__ b1,
                                                      const _Float16* __restrict__ wbh,
                                                      const float* __restrict__ b2,
                                                      _Float16* __restrict__ f2n,
                                                      size_t f2n_bstride, int batch0) {
    __shared__ __align__(16) char smem[34112];
    char* f1t = smem;                                  // 10*34*80 = 27200 B (h-only)
    unsigned* xhl = (unsigned*)(smem + 27200);         // [4][12][36] u32 (raw f32 bits)
    int tid = threadIdx.x;
    int lane = tid & 63;
    int wid = tid >> 6;
    int bx = blockIdx.x * 32, by = blockIdx.y * 8;
    int n = lane & 15, cg = lane >> 4;
    int m = lane & 15, b = lane >> 4;
    const float* xb = x + (size_t)(batch0 + blockIdx.z) * 4 * HW;
    _Float16* f2nb = f2n + (size_t)blockIdx.z * f2n_bstride;

    // phase 1: stage x halo (rows by-2..by+9, cols bx-2..bx+33) as raw f32 bits
    {
        int idx = tid;
        int r = tid / 36, c = tid - r * 36, ci = 0;
#pragma unroll
        for (int it = 0; it < 7; ++it) {
            if (idx < 1728) {
                int gy = by + r - 2, gx = bx + c - 2;
                float v = 0.f;
                if ((unsigned)gy < H && (unsigned)gx < W) v = xb[ci * HW + gy * W + gx];
                xhl[idx] = __builtin_bit_cast(unsigned, v);
            }
            idx += 256;
            c += 4; if (c >= 36) { c -= 36; r += 1; }
            r += 7; if (r >= 12) { r -= 12; ci += 1; }
        }
    }

    half8 Wf00 = *(const half8*)(w1a + (0 * 64 + lane) * 8);
    half8 Wf01 = *(const half8*)(w1a + (1 * 64 + lane) * 8);
    half8 Wf10 = *(const half8*)(w1a + (2 * 64 + lane) * 8);
    half8 Wf11 = *(const half8*)(w1a + (3 * 64 + lane) * 8);
    float bias1[8];
#pragma unroll
    for (int h = 0; h < 2; h++)
#pragma unroll
        for (int j = 0; j < 4; j++)
            bias1[h * 4 + j] = b1[h * 16 + cg * 4 + j];
    half8 Bh[9];
#pragma unroll
    for (int t = 0; t < 9; t++)
        Bh[t] = *(const half8*)(wbh + (t * 64 + lane) * 8);
    f32x4 binit;
#pragma unroll
    for (int j = 0; j < 4; j++) binit[j] = b2[b * 4 + j];

    int t0 = 2 * cg, t1 = 2 * cg + 1;
    int dy0 = (t0 * 11) >> 5, dx0 = t0 - 3 * dy0;
    int dy1 = (t1 * 11) >> 5, dx1 = t1 - 3 * dy1;
    int off0 = dy0 * 36 + dx0, off1 = dy1 * 36 + dx1;
    __syncthreads();

    // phase 2: conv1 via MFMA; 22 tiles of 16 px cover the 340-px halo
#pragma unroll 1
    for (int tt = wid; tt < 22; tt += 4) {
        int p = tt * 16 + n;
        bool valid = p < 340;
        int pc = valid ? p : 339;
        int ry = pc / 34, cx = pc - ry * 34;
        int gy = by + ry - 1, gx = bx + cx - 1;
        bool ok = ((unsigned)gy < H) && ((unsigned)gx < W);
        int base = ry * 36 + cx;
        unsigned u0[8];
#pragma unroll
        for (int j = 0; j < 8; j++)
            u0[j] = xhl[(j & 3) * 432 + base + ((j < 4) ? off0 : off1)];
        half8 Xh0 = cvt8(u0);
        half8 Xh1 = {0, 0, 0, 0, 0, 0, 0, 0};
        if (cg == 0) {
            unsigned u1[4];
#pragma unroll
            for (int j = 0; j < 4; j++)
                u1[j] = xhl[j * 432 + base + 74];       // tap 8 (dy=2,dx=2)
            Xh1 = cvt4(u1);
        }
        f32x4 d0, d1;
#pragma unroll
        for (int j = 0; j < 4; j++) { d0[j] = bias1[j]; d1[j] = bias1[4 + j]; }
        d0 = __builtin_amdgcn_mfma_f32_16x16x32_f16(Wf00, Xh0, d0, 0, 0, 0);
        d0 = __builtin_amdgcn_mfma_f32_16x16x32_f16(Wf10, Xh1, d0, 0, 0, 0);
        d1 = __builtin_amdgcn_mfma_f32_16x16x32_f16(Wf01, Xh0, d1, 0, 0, 0);
        d1 = __builtin_amdgcn_mfma_f32_16x16x32_f16(Wf11, Xh1, d1, 0, 0, 0);
        if (valid) {
            char* pxb = f1t + ry * 2720 + cx * 80;
#pragma unroll
            for (int h = 0; h < 2; h++) {
                f32x4 d = h ? d1 : d0;
                half4 hq;
#pragma unroll
                for (int j = 0; j < 4; j++) {
                    float v = d[j];
                    v = fmaxf(v, 0.2f * v);
                    v = ok ? v : 0.f;
                    hq[j] = (_Float16)v;
                }
                *(half4*)(pxb + (h * 4 + cg) * 8) = hq;
            }
        }
    }
    __syncthreads();

    // phase 3: conv2 via rolling-row f16 MFMA, D = W*X (lane owns px, 4 co)
    int wx = wid & 1, wy = wid >> 1;
    f32x4 acc2[4];
#pragma unroll
    for (int r = 0; r < 4; r++) acc2[r] = binit;
#pragma unroll
    for (int iy = 0; iy < 6; iy++) {
        int f1row = wy * 4 + iy;
        half8 ah[3];
#pragma unroll
        for (int kx = 0; kx < 3; kx++) {
            int pxi = wx * 16 + m + kx;
            ah[kx] = *(const half8*)(f1t + f1row * 2720 + pxi * 80 + b * 16);
        }
#pragma unroll
        for (int kx = 0; kx < 3; kx++) {
#pragma unroll
            for (int ry = 0; ry < 4; ry++) {
                if (ry >= iy - 2 && ry <= iy) {
                    const int t = (iy - ry) * 3 + kx;
                    acc2[ry] = __builtin_amdgcn_mfma_f32_16x16x32_f16(Bh[t], ah[kx], acc2[ry], 0, 0, 0);
                }
            }
        }
    }

    // epilogue (h-only f2n): leaky -> f16 -> direct store, 32B/px
    int x0 = bx + wx * 16 + m;
    int y0 = by + wy * 4;
    int co_off = b * 4;
#pragma unroll
    for (int ry = 0; ry < 4; ry++) {
        half4 hq;
#pragma unroll
        for (int j = 0; j < 4; j++) {
            float v = acc2[ry][j];
            v = fmaxf(v, 0.2f * v);
            hq[j] = (_Float16)v;
        }
        *(half4*)(f2nb + ((size_t)(y0 + ry) * W + x0) * 16 + co_off) = hq;
    }
}

// ---------------- conv3: h-only f16 MFMA, 32x8 tile, f16 output ----------------
__global__ __launch_bounds__(256) void conv3_mfma(const _Float16* __restrict__ f2n,
                                                  size_t f2n_bstride, int batch0,
                                                  const _Float16* __restrict__ w3f,
                                                  const float* __restrict__ bias,
                                                  _Float16* __restrict__ f3all) {
    __shared__ __align__(16) char st[10 * 34 * 40];    // 13600 B
    int tid = threadIdx.x;
    int lane = tid & 63;
    int wid = tid >> 6;
    int bx = blockIdx.x * 32, by = blockIdx.y * 8;
    const _Float16* f2nb = f2n + (size_t)blockIdx.z * f2n_bstride;
    _Float16* f3 = f3all + (size_t)(batch0 + blockIdx.z) * 8 * HW;

    // stage: rows by-1..by+8, px bx-1..bx+32, 2 x 16B chunks per px (680 tasks)
    for (int idx = tid; idx < 680; idx += 256) {
        int c0 = idx & 1;
        int rp = idx >> 1;
        int r = rp / 34, p = rp - r * 34;
        int gy = by + r - 1, gx = bx + p - 1;
        half8 v = {0, 0, 0, 0, 0, 0, 0, 0};
        if ((unsigned)gy < H && (unsigned)gx < W)
            v = *(const half8*)(f2nb + ((size_t)gy * W + gx) * 16 + c0 * 8);
        *(half8*)(st + r * 1360 + p * 40 + c0 * 16) = v;
    }

    half8 F0[3], F1[3];                                // per ky: grp0-h, grp1-h
#pragma unroll
    for (int ky = 0; ky < 3; ky++) {
        F0[ky] = *(const half8*)(w3f + ((ky * 2 + 0) * 64 + lane) * 8);
        F1[ky] = *(const half8*)(w3f + ((ky * 2 + 1) * 64 + lane) * 8);
    }
    int m = lane & 15, b = lane >> 4;
    int halfco = b & 1, kxp = b >> 1;
    int wx = wid & 1, wy = wid >> 1;
    float bc = (m < 8) ? bias[m] : 0.f;
    f32x4 acc[4];
#pragma unroll
    for (int r = 0; r < 4; r++) acc[r] = (f32x4){bc, bc, bc, bc};
    int pA = wx * 16 + m + kxp;                        // halo-local px for A (kx -1,0)
    int pB = wx * 16 + m + 2;                          // halo-local px for B (kx +1)
    __syncthreads();

#pragma unroll
    for (int iy = 0; iy < 6; iy++) {
        const char* rp = st + (wy * 4 + iy) * 1360;
        half8 ka_h = *(const half8*)(rp + pA * 40 + halfco * 16);
        half8 kb_h = *(const half8*)(rp + pB * 40 + halfco * 16);
#pragma unroll
        for (int ry = 0; ry < 4; ry++) {
            if (ry >= iy - 2 && ry <= iy) {
                const int ky = iy - ry;
                acc[ry] = __builtin_amdgcn_mfma_f32_16x16x32_f16(ka_h, F0[ky], acc[ry], 0, 0, 0);
                acc[ry] = __builtin_amdgcn_mfma_f32_16x16x32_f16(kb_h, F1[ky], acc[ry], 0, 0, 0);
            }
        }
    }

    if (m < 8) {
#pragma unroll
        for (int ry = 0; ry < 4; ry++) {
            int y = by + wy * 4 + ry;
            half4 hv = {(_Float16)acc[ry][0], (_Float16)acc[ry][1],
                        (_Float16)acc[ry][2], (_Float16)acc[ry][3]};
            *(half4*)(f3 + (size_t)m * HW + (size_t)y * W + bx + wx * 16 + b * 4) = hv;
        }
    }
}

// ---------------- stdfuse v6: f16 raw tile + packed-f16 hsq (LDS ~24 KB -> 6 blocks/CU) ----------------
__global__ __launch_bounds__(256) void stdfuse_fused(const _Float16* __restrict__ f3all,
                                                     const float* __restrict__ fw,
                                                     const float* __restrict__ fb,
                                                     const float* __restrict__ stats,
                                                     float* __restrict__ out) {
    __shared__ __align__(16) _Float16 raw[46 * 50];
    __shared__ __align__(16) _Float16 hsqh[3][46 * 68];
    __shared__ int rowOff[46];      // reflected gy * W (element offset)
    __shared__ int gxcol[46];       // reflected gx
    int tid = threadIdx.x;
    int xq = tid & 15, yp = tid >> 4;
    int bx = blockIdx.x * 32, by = blockIdx.y * 32;
    int batch = blockIdx.z;
    const _Float16* f3 = f3all + (size_t)batch * 8 * HW;

    if (tid < 46) {
        int gy = by + tid - 7;
        gy = gy < 0 ? -gy : (gy > 1023 ? 2046 - gy : gy);
        rowOff[tid] = gy * W;
        int gx = bx + tid - 7;
        gx = gx < 0 ? -gx : (gx > 1023 ? 2046 - gx : gx);
        gxcol[tid] = gx;
    }
    __syncthreads();

    // per-thread staging task table (channel-invariant): 2116 = 8*256 + 68 tasks
    int goffB[9];   // global byte offset within a channel plane (f16)
    int laddB[9];   // LDS byte offset into raw (f16)
    const bool k8 = tid < 68;
#pragma unroll
    for (int k = 0; k < 9; k++) {
        int idx = tid + k * 256;
        int idc = idx < 2116 ? idx : 2115;
        int r = idc / 46, c = idc - r * 46;
        goffB[k] = (rowOff[r] + gxcol[c]) * 2;
        laddB[k] = (r * 50 + c) * 2;
    }

    float wwin[3] = {fw[0] * 0.125f, fw[1] * 0.125f, fw[2] * 0.125f};
    float part[4] = {0.f, 0.f, 0.f, 0.f};

    // prologue: load channel 0 into registers (raw f16 bits, no conversion)
    unsigned short stg[9];
    {
        const char* src = (const char*)f3;
#pragma unroll
        for (int k = 0; k < 8; k++) stg[k] = *(const unsigned short*)(src + goffB[k]);
        stg[8] = k8 ? *(const unsigned short*)(src + goffB[8]) : (unsigned short)0;
    }

    for (int z = 0; z < 8; z++) {
        // write staged registers to raw (safe: prior phase-2 raw reads ended at barrier B)
        char* rb = (char*)raw;
#pragma unroll
        for (int k = 0; k < 8; k++) *(unsigned short*)(rb + laddB[k]) = stg[k];
        if (k8) *(unsigned short*)(rb + laddB[8]) = stg[8];

        // T14: issue next channel's loads BEFORE the barrier; latency hides under phase 2+3
        if (z < 7) {
            const char* nsrc = (const char*)(f3 + (size_t)(z + 1) * HW);
#pragma unroll
            for (int k = 0; k < 8; k++) stg[k] = *(const unsigned short*)(nsrc + goffB[k]);
            if (k8) stg[8] = *(const unsigned short*)(nsrc + goffB[8]);
        }
        __syncthreads();   // A: raw ready; prior phase-3 hsqh reads complete

        // phase 2: horizontal window sums (f32) -> packed f16 {sA,sB,qA,qB} per window
        for (int idx = tid; idx < 736; idx += 256) {
            int r = idx >> 4, xh = idx & 15;
            const _Float16* rp = raw + r * 50 + 2 * xh;
            float v[16], w[16];
#pragma unroll
            for (int k = 0; k < 8; k++) {
                h2 p = *(const h2*)(rp + 2 * k);
                v[2 * k] = (float)p[0]; v[2 * k + 1] = (float)p[1];
            }
#pragma unroll
            for (int k = 0; k < 16; k++) w[k] = v[k] * v[k];
            float ms = v[6] + v[7] + v[8] + v[9];
            float mq = w[6] + w[7] + w[8] + w[9];
            float sA5 = v[5] + ms, sB5 = ms + v[10];
            float qA5 = w[5] + mq, qB5 = mq + w[10];
            float sA9 = sA5 + v[3] + v[4] + v[10] + v[11];
            float sB9 = sB5 + v[4] + v[5] + v[11] + v[12];
            float qA9 = qA5 + w[3] + w[4] + w[10] + w[11];
            float qB9 = qB5 + w[4] + w[5] + w[11] + w[12];
            float sA15 = sA9 + v[0] + v[1] + v[2] + v[12] + v[13] + v[14];
            float sB15 = sB9 + v[1] + v[2] + v[3] + v[13] + v[14] + v[15];
            float qA15 = qA9 + w[0] + w[1] + w[2] + w[12] + w[13] + w[14];
            float qB15 = qB9 + w[1] + w[2] + w[3] + w[13] + w[14] + w[15];
            int ho = r * 68 + 4 * xh;
            *(half4*)&hsqh[0][ho] = (half4){(_Float16)sA5,  (_Float16)sB5,  (_Float16)qA5,  (_Float16)qB5};
            *(half4*)&hsqh[1][ho] = (half4){(_Float16)sA9,  (_Float16)sB9,  (_Float16)qA9,  (_Float16)qB9};
            *(half4*)&hsqh[2][ho] = (half4){(_Float16)sA15, (_Float16)sB15, (_Float16)qA15, (_Float16)qB15};
        }
        __syncthreads();   // B: hsqh ready; all raw reads complete

        // phase 3: vertical sums in packed f16 (dual accumulators) + f32 finishing
#pragma unroll
        for (int wi = 0; wi < 3; wi++) {
            const int wlen = (wi == 0) ? 5 : ((wi == 1) ? 9 : 15);
            const int r0 = 2 * yp + 7 - (wlen >> 1);
            const float inv = 1.0f / (float)(wlen * wlen);
            const float ww = wwin[wi];
            const _Float16* basep = &hsqh[wi][4 * xq];
            half4 first = *(const half4*)(basep + r0 * 68);
            half4 e = first;
            half4 o = *(const half4*)(basep + (r0 + 1) * 68);
#pragma unroll
            for (int k = 2; k + 1 < wlen; k += 2) {
                e += *(const half4*)(basep + (r0 + k) * 68);
                o += *(const half4*)(basep + (r0 + k + 1) * 68);
            }
            e += *(const half4*)(basep + (r0 + wlen - 1) * 68);   // last even row
            half4 tot = e + o;
            half4 last = *(const half4*)(basep + (r0 + wlen) * 68);
            half4 sh = tot - first + last;
            float sA0 = (float)tot[0], sB0 = (float)tot[1];
            float qA0 = (float)tot[2], qB0 = (float)tot[3];
            float sA1 = (float)sh[0],  sB1 = (float)sh[1];
            float qA1 = (float)sh[2],  qB1 = (float)sh[3];
            float mA0 = sA0 * inv, m2A0 = qA0 * inv;
            part[0] += ww * fast_sqrtf(fmaxf(m2A0 - mA0 * mA0, 0.f) + 1e-8f);
            float mB0 = sB0 * inv, m2B0 = qB0 * inv;
            part[1] += ww * fast_sqrtf(fmaxf(m2B0 - mB0 * mB0, 0.f) + 1e-8f);
            float mA1 = sA1 * inv, m2A1 = qA1 * inv;
            part[2] += ww * fast_sqrtf(fmaxf(m2A1 - mA1 * mA1, 0.f) + 1e-8f);
            float mB1 = sB1 * inv, m2B1 = qB1 * inv;
            part[3] += ww * fast_sqrtf(fmaxf(m2B1 - mB1 * mB1, 0.f) + 1e-8f);
        }
        // no barrier: next iter writes raw (disjoint from hsqh); hsqh rewritten only after next barrier A
    }

    // epilogue: fused value -> per-channel threshold + sigmoid, direct output write
    float fb0 = fb[0];
    int gy = by + 2 * yp, gx = bx + 2 * xq;
#pragma unroll
    for (int c = 0; c < 4; c++) {
        float lo = stats[(batch * 4 + c) * 2];
        float up = stats[(batch * 4 + c) * 2 + 1];
        float inv = 1.f / (up - lo);
        float v[4];
#pragma unroll
        for (int p = 0; p < 4; p++) {
            float ns = (part[p] + fb0 - lo) * inv;
            ns = fminf(fmaxf(ns, 0.f), 1.f);
            v[p] = 1.f / (1.f + fast_expf(3.f - 6.f * ns));
        }
        float* plane = out + ((size_t)(batch * 4 + c)) * HW;
        *(float2*)(plane + (size_t)gy * W + gx) = make_float2(v[0], v[1]);
        *(float2*)(plane + (size_t)(gy + 1) * W + gx) = make_float2(v[2], v[3]);
    }
}

extern "C" void kernel_launch(void* const* d_in, const int* in_sizes, int n_in,
                              void* d_out, int out_size, void* d_ws, size_t ws_size,
                              hipStream_t stream) {
    (void)in_sizes; (void)n_in; (void)out_size;
    const float* x = (const float*)d_in[0];
    const float* w1 = (const float*)d_in[1];
    const float* b1 = (const float*)d_in[2];
    const float* w2 = (const float*)d_in[3];
    const float* b2 = (const float*)d_in[4];
    const float* w3 = (const float*)d_in[5];
    const float* b3 = (const float*)d_in[6];
    const float* chw = (const float*)d_in[7];
    const float* fw = (const float*)d_in[8];
    const float* fb = (const float*)d_in[9];
    float* out = (float*)d_out;

    char* ws = (char*)d_ws;
    float* stats = (float*)ws;                         // 32 f
    double* part = (double*)(ws + 256);                // 1024 d, ends 8448
    _Float16* w1a = (_Float16*)(ws + 8448);            // 2048 f16, ends 12544
    _Float16* w3f = (_Float16*)(ws + 24832);           // 3072 f16, ends 30976
    _Float16* w2bh = (_Float16*)(ws + 37120);          // 4608 f16, ends 46336
    _Float16* f3all = (_Float16*)(ws + 65536);         // 4 batches x 8 ch x HW f16 = 64 MB
    _Float16* f2n = (_Float16*)(ws + 67174400);        // h-only planes of 32 MB

    // wide mode: 4 f2n planes -> single conv12 + single conv3 dispatch (needs 192.05 MB ws)
    const size_t PLANE = (size_t)16 * HW;              // f16 elements per f2n plane
    const size_t WIDE_WS = 67174400ULL + 4ULL * PLANE * sizeof(_Float16);
    bool wide = ws_size >= WIDE_WS;

    stats_partial<<<512, 256, 0, stream>>>(x, part);
    stats_final_prep<<<1, 256, 0, stream>>>(part, chw, w1, w2, w3, stats, w1a, w3f, w2bh);

    if (wide) {
        conv12_mfma<<<dim3(32, 128, 4), 256, 0, stream>>>(x, w1a, b1, w2bh, b2, f2n, PLANE, 0);
        conv3_mfma<<<dim3(32, 128, 4), 256, 0, stream>>>(f2n, PLANE, 0, w3f, b3, f3all);
    } else {
        for (int b = 0; b < 4; b++) {
            conv12_mfma<<<dim3(32, 128, 1), 256, 0, stream>>>(x, w1a, b1, w2bh, b2, f2n, 0, b);
            conv3_mfma<<<dim3(32, 128, 1), 256, 0, stream>>>(f2n, 0, b, w3f, b3, f3all);
        }
    }
    stdfuse_fused<<<dim3(32, 32, 4), 256, 0, stream>>>(f3all, fw, fb, stats, out);
}

// Round 11
// 326.578 us; speedup vs baseline: 1.5900x; 1.0900x over previous
//
#include <hip/hip_runtime.h>
#include <math.h>

#define H 1024
#define W 1024
#define HW (H * W)

typedef _Float16 half8 __attribute__((ext_vector_type(8)));
typedef _Float16 half4 __attribute__((ext_vector_type(4)));
typedef _Float16 h2 __attribute__((ext_vector_type(2)));
typedef float f32x4 __attribute__((ext_vector_type(4)));
typedef unsigned uint4v __attribute__((ext_vector_type(4)));

__device__ __forceinline__ float fast_sqrtf(float x) { return __builtin_amdgcn_sqrtf(x); }
__device__ __forceinline__ float fast_expf(float x) { return __builtin_amdgcn_exp2f(x * 1.44269504088896340736f); }

__device__ __forceinline__ h2 pkrtz(float a, float b) {
    return __builtin_bit_cast(h2, __builtin_amdgcn_cvt_pkrtz(a, b));
}

// ---------------- stats pass 1: partial sum/sumsq per (b,c) chunk ----------------
__global__ __launch_bounds__(256) void stats_partial(const float* __restrict__ x,
                                                     double* __restrict__ part) {
    int blk = blockIdx.x;
    int bc = blk >> 5;
    int j = blk & 31;
    const float* p = x + (size_t)bc * HW + (size_t)j * (HW / 32);
    int tid = threadIdx.x;
    double s = 0.0, q = 0.0;
    const float4* p4 = (const float4*)p;
    for (int i = tid; i < (HW / 32) / 4; i += 256) {
        float4 v = p4[i];
        s += (double)v.x + (double)v.y + (double)v.z + (double)v.w;
        q += (double)v.x * v.x + (double)v.y * v.y + (double)v.z * v.z + (double)v.w * v.w;
    }
    __shared__ double ls[256], lq[256];
    ls[tid] = s;
    lq[tid] = q;
    __syncthreads();
    for (int ofs = 128; ofs > 0; ofs >>= 1) {
        if (tid < ofs) { ls[tid] += ls[tid + ofs]; lq[tid] += lq[tid + ofs]; }
        __syncthreads();
    }
    if (tid == 0) {
        part[blk * 2] = ls[0];
        part[blk * 2 + 1] = lq[0];
    }
}

// ---------------- stats pass 2 + weight prep (h-only conv weights) ----------------
__global__ __launch_bounds__(256) void stats_final_prep(const double* __restrict__ part,
                                                        const float* __restrict__ chw,
                                                        const float* __restrict__ w1,
                                                        const float* __restrict__ w2,
                                                        const float* __restrict__ w3,
                                                        float* __restrict__ stats,
                                                        _Float16* __restrict__ w1a,
                                                        _Float16* __restrict__ w3f,
                                                        _Float16* __restrict__ w2bh) {
    int tid = threadIdx.x;
    __shared__ float cw[4];
    if (tid == 0) {
        float m = fmaxf(fmaxf(chw[0], chw[1]), fmaxf(chw[2], chw[3]));
        float e0 = expf(chw[0] - m), e1 = expf(chw[1] - m);
        float e2 = expf(chw[2] - m), e3 = expf(chw[3] - m);
        float s = e0 + e1 + e2 + e3;
        cw[0] = e0 / s; cw[1] = e1 / s; cw[2] = e2 / s; cw[3] = e3 / s;
    }
    __syncthreads();
    if (tid < 16) {
        double s = 0.0, q = 0.0;
        for (int j = 0; j < 32; j++) {
            s += part[(tid * 32 + j) * 2];
            q += part[(tid * 32 + j) * 2 + 1];
        }
        double n = (double)HW;
        double var = (q - s * s / n) / (n - 1.0);
        if (var < 0) var = 0;
        float gs = (float)sqrt(var);
        int c = tid & 3;
        float gf = fminf(fmaxf(gs * 5.0f, 0.5f), 2.0f);
        float cf = fminf(fmaxf(gs * cw[c] * 2.0f, 0.8f), 1.2f);
        stats[tid * 2] = 0.05f * gf * cf;
        stats[tid * 2 + 1] = 0.20f * gf * cf;
    }
    // conv1 A-frags, h-only: 4 sets (c,h) of 64 lanes x 8
    for (int i = tid; i < 256; i += 256) {
        int s = i >> 6, l = i & 63;
        int c = s >> 1, h = s & 1;
        int m = l & 15, cg = l >> 4;
        int co = h * 16 + m;
#pragma unroll
        for (int j = 0; j < 8; j++) {
            int k = c * 32 + cg * 8 + j;
            float v = 0.f;
            if (k < 36) {
                int t = k >> 2, ci = k & 3;
                v = w1[(co * 4 + ci) * 9 + t];
            }
            w1a[i * 8 + j] = (_Float16)v;
        }
    }
    for (int idx = tid; idx < 576; idx += 256) {           // conv2 B-frags (h only)
        int t = idx >> 6, l = idx & 63;
        int co = l & 15, cg = l >> 4;
#pragma unroll
        for (int j = 0; j < 8; j++) {
            int ci = cg * 8 + j;
            w2bh[idx * 8 + j] = (_Float16)w2[(co * 32 + ci) * 9 + t];
        }
    }
    for (int idx = tid; idx < 384; idx += 256) {           // conv3 B-frags: 6 sets (ky,grp) h-only
        int t = idx >> 6, l = idx & 63;
        int ky = t / 2, grp = t & 1;
        int co = l & 15, bq = l >> 4;
#pragma unroll
        for (int j = 0; j < 8; j++) {
            int k = bq * 8 + j;
            float v = 0.f;
            if (co < 8) {
                if (grp == 0) {
                    int kxp = k >> 4, ci = k & 15;
                    v = w3[((co * 16 + ci) * 3 + ky) * 3 + kxp];
                } else if (k < 16) {
                    v = w3[((co * 16 + k) * 3 + ky) * 3 + 2];
                }
            }
            w3f[idx * 8 + j] = (_Float16)v;
        }
    }
}

// ---------------- fused conv1+conv2, f16 h-only MFMA ----------------
// v11: x halo staged as channel-pair-packed f16 (xp01 = ch0|ch1, xp23 = ch2|ch3).
// MFMA A-operand assembles from 4 (+2) ds_read_b32 with ZERO unpack VALU.
// smem 30.7 KB -> 5 blocks/CU.
__global__ __launch_bounds__(256, 5) void conv12_mfma(const float* __restrict__ x,
                                                      const _Float16* __restrict__ w1a,
                                                      const float* __restrict__ b1,
                                                      const _Float16* __restrict__ wbh,
                                                      const float* __restrict__ b2,
                                                      _Float16* __restrict__ f2n,
                                                      size_t f2n_bstride, int batch0) {
    __shared__ __align__(16) char smem[30656];
    char* f1t = smem;                                  // 10*34*80 = 27200 B (h-only)
    unsigned* xp = (unsigned*)(smem + 27200);          // 2 planes x [12][36] u32 packed f16 pairs
    int tid = threadIdx.x;
    int lane = tid & 63;
    int wid = tid >> 6;
    int bx = blockIdx.x * 32, by = blockIdx.y * 8;
    int n = lane & 15, cg = lane >> 4;
    int m = lane & 15, b = lane >> 4;
    const float* xb = x + (size_t)(batch0 + blockIdx.z) * 4 * HW;
    _Float16* f2nb = f2n + (size_t)blockIdx.z * f2n_bstride;

    // phase 1: stage x halo (rows by-2..by+9, cols bx-2..bx+33) as packed f16 channel pairs
    // idx = plane*432 + r*36 + c, plane 0 -> (ch0,ch1), plane 1 -> (ch2,ch3); 864 tasks
    {
        int idx = tid;
        int r = tid / 36, c = tid - r * 36, plane = 0;
#pragma unroll
        for (int it = 0; it < 4; ++it) {
            if (idx < 864) {
                int gy = by + r - 2, gx = bx + c - 2;
                float v0 = 0.f, v1 = 0.f;
                if ((unsigned)gy < H && (unsigned)gx < W) {
                    const float* pp = xb + (size_t)(2 * plane) * HW + gy * W + gx;
                    v0 = pp[0];
                    v1 = pp[HW];
                }
                xp[idx] = __builtin_bit_cast(unsigned, pkrtz(v0, v1));
            }
            idx += 256;
            c += 4; if (c >= 36) { c -= 36; r += 1; }
            r += 7; if (r >= 12) { r -= 12; plane += 1; }
        }
    }

    half8 Wf00 = *(const half8*)(w1a + (0 * 64 + lane) * 8);
    half8 Wf01 = *(const half8*)(w1a + (1 * 64 + lane) * 8);
    half8 Wf10 = *(const half8*)(w1a + (2 * 64 + lane) * 8);
    half8 Wf11 = *(const half8*)(w1a + (3 * 64 + lane) * 8);
    float bias1[8];
#pragma unroll
    for (int h = 0; h < 2; h++)
#pragma unroll
        for (int j = 0; j < 4; j++)
            bias1[h * 4 + j] = b1[h * 16 + cg * 4 + j];
    half8 Bh[9];
#pragma unroll
    for (int t = 0; t < 9; t++)
        Bh[t] = *(const half8*)(wbh + (t * 64 + lane) * 8);
    f32x4 binit;
#pragma unroll
    for (int j = 0; j < 4; j++) binit[j] = b2[b * 4 + j];

    int t0 = 2 * cg, t1 = 2 * cg + 1;
    int dy0 = (t0 * 11) >> 5, dx0 = t0 - 3 * dy0;
    int dy1 = (t1 * 11) >> 5, dx1 = t1 - 3 * dy1;
    int off0 = dy0 * 36 + dx0, off1 = dy1 * 36 + dx1;
    __syncthreads();

    // phase 2: conv1 via MFMA; 22 tiles of 16 px cover the 340-px halo.
    // A-operand: {xp01[off0], xp23[off0], xp01[off1], xp23[off1]} -> half8, no unpack.
#pragma unroll 1
    for (int tt = wid; tt < 22; tt += 4) {
        int p = tt * 16 + n;
        bool valid = p < 340;
        int pc = valid ? p : 339;
        int ry = pc / 34, cx = pc - ry * 34;
        int gy = by + ry - 1, gx = bx + cx - 1;
        bool ok = ((unsigned)gy < H) && ((unsigned)gx < W);
        int base = ry * 36 + cx;
        uint4v uv;
        uv.x = xp[base + off0];
        uv.y = xp[432 + base + off0];
        uv.z = xp[base + off1];
        uv.w = xp[432 + base + off1];
        half8 Xh0 = __builtin_bit_cast(half8, uv);
        half8 Xh1 = {0, 0, 0, 0, 0, 0, 0, 0};
        if (cg == 0) {
            uint4v uw = {0, 0, 0, 0};
            uw.x = xp[base + 74];                      // tap 8 (dy=2,dx=2), ch0|ch1
            uw.y = xp[432 + base + 74];                // ch2|ch3
            Xh1 = __builtin_bit_cast(half8, uw);
        }
        f32x4 d0, d1;
#pragma unroll
        for (int j = 0; j < 4; j++) { d0[j] = bias1[j]; d1[j] = bias1[4 + j]; }
        d0 = __builtin_amdgcn_mfma_f32_16x16x32_f16(Wf00, Xh0, d0, 0, 0, 0);
        d0 = __builtin_amdgcn_mfma_f32_16x16x32_f16(Wf10, Xh1, d0, 0, 0, 0);
        d1 = __builtin_amdgcn_mfma_f32_16x16x32_f16(Wf01, Xh0, d1, 0, 0, 0);
        d1 = __builtin_amdgcn_mfma_f32_16x16x32_f16(Wf11, Xh1, d1, 0, 0, 0);
        if (valid) {
            char* pxb = f1t + ry * 2720 + cx * 80;
#pragma unroll
            for (int h = 0; h < 2; h++) {
                f32x4 d = h ? d1 : d0;
                half4 hq;
#pragma unroll
                for (int j = 0; j < 4; j++) {
                    float v = d[j];
                    v = fmaxf(v, 0.2f * v);
                    v = ok ? v : 0.f;
                    hq[j] = (_Float16)v;
                }
                *(half4*)(pxb + (h * 4 + cg) * 8) = hq;
            }
        }
    }
    __syncthreads();

    // phase 3: conv2 via rolling-row f16 MFMA, D = W*X (lane owns px, 4 co)
    int wx = wid & 1, wy = wid >> 1;
    f32x4 acc2[4];
#pragma unroll
    for (int r = 0; r < 4; r++) acc2[r] = binit;
#pragma unroll
    for (int iy = 0; iy < 6; iy++) {
        int f1row = wy * 4 + iy;
        half8 ah[3];
#pragma unroll
        for (int kx = 0; kx < 3; kx++) {
            int pxi = wx * 16 + m + kx;
            ah[kx] = *(const half8*)(f1t + f1row * 2720 + pxi * 80 + b * 16);
        }
#pragma unroll
        for (int kx = 0; kx < 3; kx++) {
#pragma unroll
            for (int ry = 0; ry < 4; ry++) {
                if (ry >= iy - 2 && ry <= iy) {
                    const int t = (iy - ry) * 3 + kx;
                    acc2[ry] = __builtin_amdgcn_mfma_f32_16x16x32_f16(Bh[t], ah[kx], acc2[ry], 0, 0, 0);
                }
            }
        }
    }

    // epilogue (h-only f2n): leaky -> f16 -> direct store, 32B/px
    int x0 = bx + wx * 16 + m;
    int y0 = by + wy * 4;
    int co_off = b * 4;
#pragma unroll
    for (int ry = 0; ry < 4; ry++) {
        half4 hq;
#pragma unroll
        for (int j = 0; j < 4; j++) {
            float v = acc2[ry][j];
            v = fmaxf(v, 0.2f * v);
            hq[j] = (_Float16)v;
        }
        *(half4*)(f2nb + ((size_t)(y0 + ry) * W + x0) * 16 + co_off) = hq;
    }
}

// ---------------- conv3: h-only f16 MFMA, 32x8 tile, f16 output ----------------
__global__ __launch_bounds__(256) void conv3_mfma(const _Float16* __restrict__ f2n,
                                                  size_t f2n_bstride, int batch0,
                                                  const _Float16* __restrict__ w3f,
                                                  const float* __restrict__ bias,
                                                  _Float16* __restrict__ f3all) {
    __shared__ __align__(16) char st[10 * 34 * 40];    // 13600 B
    int tid = threadIdx.x;
    int lane = tid & 63;
    int wid = tid >> 6;
    int bx = blockIdx.x * 32, by = blockIdx.y * 8;
    const _Float16* f2nb = f2n + (size_t)blockIdx.z * f2n_bstride;
    _Float16* f3 = f3all + (size_t)(batch0 + blockIdx.z) * 8 * HW;

    // stage: rows by-1..by+8, px bx-1..bx+32, 2 x 16B chunks per px (680 tasks)
    for (int idx = tid; idx < 680; idx += 256) {
        int c0 = idx & 1;
        int rp = idx >> 1;
        int r = rp / 34, p = rp - r * 34;
        int gy = by + r - 1, gx = bx + p - 1;
        half8 v = {0, 0, 0, 0, 0, 0, 0, 0};
        if ((unsigned)gy < H && (unsigned)gx < W)
            v = *(const half8*)(f2nb + ((size_t)gy * W + gx) * 16 + c0 * 8);
        *(half8*)(st + r * 1360 + p * 40 + c0 * 16) = v;
    }

    half8 F0[3], F1[3];                                // per ky: grp0-h, grp1-h
#pragma unroll
    for (int ky = 0; ky < 3; ky++) {
        F0[ky] = *(const half8*)(w3f + ((ky * 2 + 0) * 64 + lane) * 8);
        F1[ky] = *(const half8*)(w3f + ((ky * 2 + 1) * 64 + lane) * 8);
    }
    int m = lane & 15, b = lane >> 4;
    int halfco = b & 1, kxp = b >> 1;
    int wx = wid & 1, wy = wid >> 1;
    float bc = (m < 8) ? bias[m] : 0.f;
    f32x4 acc[4];
#pragma unroll
    for (int r = 0; r < 4; r++) acc[r] = (f32x4){bc, bc, bc, bc};
    int pA = wx * 16 + m + kxp;                        // halo-local px for A (kx -1,0)
    int pB = wx * 16 + m + 2;                          // halo-local px for B (kx +1)
    __syncthreads();

#pragma unroll
    for (int iy = 0; iy < 6; iy++) {
        const char* rp = st + (wy * 4 + iy) * 1360;
        half8 ka_h = *(const half8*)(rp + pA * 40 + halfco * 16);
        half8 kb_h = *(const half8*)(rp + pB * 40 + halfco * 16);
#pragma unroll
        for (int ry = 0; ry < 4; ry++) {
            if (ry >= iy - 2 && ry <= iy) {
                const int ky = iy - ry;
                acc[ry] = __builtin_amdgcn_mfma_f32_16x16x32_f16(ka_h, F0[ky], acc[ry], 0, 0, 0);
                acc[ry] = __builtin_amdgcn_mfma_f32_16x16x32_f16(kb_h, F1[ky], acc[ry], 0, 0, 0);
            }
        }
    }

    if (m < 8) {
#pragma unroll
        for (int ry = 0; ry < 4; ry++) {
            int y = by + wy * 4 + ry;
            half4 hv = {(_Float16)acc[ry][0], (_Float16)acc[ry][1],
                        (_Float16)acc[ry][2], (_Float16)acc[ry][3]};
            *(half4*)(f3 + (size_t)m * HW + (size_t)y * W + bx + wx * 16 + b * 4) = hv;
        }
    }
}

// ---------------- stdfuse v6: f16 raw tile + packed-f16 hsq (LDS ~24 KB -> 6 blocks/CU) ----------------
__global__ __launch_bounds__(256) void stdfuse_fused(const _Float16* __restrict__ f3all,
                                                     const float* __restrict__ fw,
                                                     const float* __restrict__ fb,
                                                     const float* __restrict__ stats,
                                                     float* __restrict__ out) {
    __shared__ __align__(16) _Float16 raw[46 * 50];
    __shared__ __align__(16) _Float16 hsqh[3][46 * 68];
    __shared__ int rowOff[46];      // reflected gy * W (element offset)
    __shared__ int gxcol[46];       // reflected gx
    int tid = threadIdx.x;
    int xq = tid & 15, yp = tid >> 4;
    int bx = blockIdx.x * 32, by = blockIdx.y * 32;
    int batch = blockIdx.z;
    const _Float16* f3 = f3all + (size_t)batch * 8 * HW;

    if (tid < 46) {
        int gy = by + tid - 7;
        gy = gy < 0 ? -gy : (gy > 1023 ? 2046 - gy : gy);
        rowOff[tid] = gy * W;
        int gx = bx + tid - 7;
        gx = gx < 0 ? -gx : (gx > 1023 ? 2046 - gx : gx);
        gxcol[tid] = gx;
    }
    __syncthreads();

    // per-thread staging task table (channel-invariant): 2116 = 8*256 + 68 tasks
    int goffB[9];   // global byte offset within a channel plane (f16)
    int laddB[9];   // LDS byte offset into raw (f16)
    const bool k8 = tid < 68;
#pragma unroll
    for (int k = 0; k < 9; k++) {
        int idx = tid + k * 256;
        int idc = idx < 2116 ? idx : 2115;
        int r = idc / 46, c = idc - r * 46;
        goffB[k] = (rowOff[r] + gxcol[c]) * 2;
        laddB[k] = (r * 50 + c) * 2;
    }

    float wwin[3] = {fw[0] * 0.125f, fw[1] * 0.125f, fw[2] * 0.125f};
    float part[4] = {0.f, 0.f, 0.f, 0.f};

    // prologue: load channel 0 into registers (raw f16 bits, no conversion)
    unsigned short stg[9];
    {
        const char* src = (const char*)f3;
#pragma unroll
        for (int k = 0; k < 8; k++) stg[k] = *(const unsigned short*)(src + goffB[k]);
        stg[8] = k8 ? *(const unsigned short*)(src + goffB[8]) : (unsigned short)0;
    }

    for (int z = 0; z < 8; z++) {
        // write staged registers to raw (safe: prior phase-2 raw reads ended at barrier B)
        char* rb = (char*)raw;
#pragma unroll
        for (int k = 0; k < 8; k++) *(unsigned short*)(rb + laddB[k]) = stg[k];
        if (k8) *(unsigned short*)(rb + laddB[8]) = stg[8];

        // T14: issue next channel's loads BEFORE the barrier; latency hides under phase 2+3
        if (z < 7) {
            const char* nsrc = (const char*)(f3 + (size_t)(z + 1) * HW);
#pragma unroll
            for (int k = 0; k < 8; k++) stg[k] = *(const unsigned short*)(nsrc + goffB[k]);
            if (k8) stg[8] = *(const unsigned short*)(nsrc + goffB[8]);
        }
        __syncthreads();   // A: raw ready; prior phase-3 hsqh reads complete

        // phase 2: horizontal window sums (f32) -> packed f16 {sA,sB,qA,qB} per window
        for (int idx = tid; idx < 736; idx += 256) {
            int r = idx >> 4, xh = idx & 15;
            const _Float16* rp = raw + r * 50 + 2 * xh;
            float v[16], w[16];
#pragma unroll
            for (int k = 0; k < 8; k++) {
                h2 p = *(const h2*)(rp + 2 * k);
                v[2 * k] = (float)p[0]; v[2 * k + 1] = (float)p[1];
            }
#pragma unroll
            for (int k = 0; k < 16; k++) w[k] = v[k] * v[k];
            float ms = v[6] + v[7] + v[8] + v[9];
            float mq = w[6] + w[7] + w[8] + w[9];
            float sA5 = v[5] + ms, sB5 = ms + v[10];
            float qA5 = w[5] + mq, qB5 = mq + w[10];
            float sA9 = sA5 + v[3] + v[4] + v[10] + v[11];
            float sB9 = sB5 + v[4] + v[5] + v[11] + v[12];
            float qA9 = qA5 + w[3] + w[4] + w[10] + w[11];
            float qB9 = qB5 + w[4] + w[5] + w[11] + w[12];
            float sA15 = sA9 + v[0] + v[1] + v[2] + v[12] + v[13] + v[14];
            float sB15 = sB9 + v[1] + v[2] + v[3] + v[13] + v[14] + v[15];
            float qA15 = qA9 + w[0] + w[1] + w[2] + w[12] + w[13] + w[14];
            float qB15 = qB9 + w[1] + w[2] + w[3] + w[13] + w[14] + w[15];
            int ho = r * 68 + 4 * xh;
            *(half4*)&hsqh[0][ho] = (half4){(_Float16)sA5,  (_Float16)sB5,  (_Float16)qA5,  (_Float16)qB5};
            *(half4*)&hsqh[1][ho] = (half4){(_Float16)sA9,  (_Float16)sB9,  (_Float16)qA9,  (_Float16)qB9};
            *(half4*)&hsqh[2][ho] = (half4){(_Float16)sA15, (_Float16)sB15, (_Float16)qA15, (_Float16)qB15};
        }
        __syncthreads();   // B: hsqh ready; all raw reads complete

        // phase 3: vertical sums in packed f16 (dual accumulators) + f32 finishing
#pragma unroll
        for (int wi = 0; wi < 3; wi++) {
            const int wlen = (wi == 0) ? 5 : ((wi == 1) ? 9 : 15);
            const int r0 = 2 * yp + 7 - (wlen >> 1);
            const float inv = 1.0f / (float)(wlen * wlen);
            const float ww = wwin[wi];
            const _Float16* basep = &hsqh[wi][4 * xq];
            half4 first = *(const half4*)(basep + r0 * 68);
            half4 e = first;
            half4 o = *(const half4*)(basep + (r0 + 1) * 68);
#pragma unroll
            for (int k = 2; k + 1 < wlen; k += 2) {
                e += *(const half4*)(basep + (r0 + k) * 68);
                o += *(const half4*)(basep + (r0 + k + 1) * 68);
            }
            e += *(const half4*)(basep + (r0 + wlen - 1) * 68);   // last even row
            half4 tot = e + o;
            half4 last = *(const half4*)(basep + (r0 + wlen) * 68);
            half4 sh = tot - first + last;
            float sA0 = (float)tot[0], sB0 = (float)tot[1];
            float qA0 = (float)tot[2], qB0 = (float)tot[3];
            float sA1 = (float)sh[0],  sB1 = (float)sh[1];
            float qA1 = (float)sh[2],  qB1 = (float)sh[3];
            float mA0 = sA0 * inv, m2A0 = qA0 * inv;
            part[0] += ww * fast_sqrtf(fmaxf(m2A0 - mA0 * mA0, 0.f) + 1e-8f);
            float mB0 = sB0 * inv, m2B0 = qB0 * inv;
            part[1] += ww * fast_sqrtf(fmaxf(m2B0 - mB0 * mB0, 0.f) + 1e-8f);
            float mA1 = sA1 * inv, m2A1 = qA1 * inv;
            part[2] += ww * fast_sqrtf(fmaxf(m2A1 - mA1 * mA1, 0.f) + 1e-8f);
            float mB1 = sB1 * inv, m2B1 = qB1 * inv;
            part[3] += ww * fast_sqrtf(fmaxf(m2B1 - mB1 * mB1, 0.f) + 1e-8f);
        }
        // no barrier: next iter writes raw (disjoint from hsqh); hsqh rewritten only after next barrier A
    }

    // epilogue: fused value -> per-channel threshold + sigmoid, direct output write
    float fb0 = fb[0];
    int gy = by + 2 * yp, gx = bx + 2 * xq;
#pragma unroll
    for (int c = 0; c < 4; c++) {
        float lo = stats[(batch * 4 + c) * 2];
        float up = stats[(batch * 4 + c) * 2 + 1];
        float inv = 1.f / (up - lo);
        float v[4];
#pragma unroll
        for (int p = 0; p < 4; p++) {
            float ns = (part[p] + fb0 - lo) * inv;
            ns = fminf(fmaxf(ns, 0.f), 1.f);
            v[p] = 1.f / (1.f + fast_expf(3.f - 6.f * ns));
        }
        float* plane = out + ((size_t)(batch * 4 + c)) * HW;
        *(float2*)(plane + (size_t)gy * W + gx) = make_float2(v[0], v[1]);
        *(float2*)(plane + (size_t)(gy + 1) * W + gx) = make_float2(v[2], v[3]);
    }
}

extern "C" void kernel_launch(void* const* d_in, const int* in_sizes, int n_in,
                              void* d_out, int out_size, void* d_ws, size_t ws_size,
                              hipStream_t stream) {
    (void)in_sizes; (void)n_in; (void)out_size;
    const float* x = (const float*)d_in[0];
    const float* w1 = (const float*)d_in[1];
    const float* b1 = (const float*)d_in[2];
    const float* w2 = (const float*)d_in[3];
    const float* b2 = (const float*)d_in[4];
    const float* w3 = (const float*)d_in[5];
    const float* b3 = (const float*)d_in[6];
    const float* chw = (const float*)d_in[7];
    const float* fw = (const float*)d_in[8];
    const float* fb = (const float*)d_in[9];
    float* out = (float*)d_out;

    char* ws = (char*)d_ws;
    float* stats = (float*)ws;                         // 32 f
    double* part = (double*)(ws + 256);                // 1024 d, ends 8448
    _Float16* w1a = (_Float16*)(ws + 8448);            // 2048 f16, ends 12544
    _Float16* w3f = (_Float16*)(ws + 24832);           // 3072 f16, ends 30976
    _Float16* w2bh = (_Float16*)(ws + 37120);          // 4608 f16, ends 46336
    _Float16* f3all = (_Float16*)(ws + 65536);         // 4 batches x 8 ch x HW f16 = 64 MB
    _Float16* f2n = (_Float16*)(ws + 67174400);        // h-only planes of 32 MB

    // wide mode: 4 f2n planes -> single conv12 + single conv3 dispatch (needs 192.05 MB ws)
    const size_t PLANE = (size_t)16 * HW;              // f16 elements per f2n plane
    const size_t WIDE_WS = 67174400ULL + 4ULL * PLANE * sizeof(_Float16);
    bool wide = ws_size >= WIDE_WS;

    stats_partial<<<512, 256, 0, stream>>>(x, part);
    stats_final_prep<<<1, 256, 0, stream>>>(part, chw, w1, w2, w3, stats, w1a, w3f, w2bh);

    if (wide) {
        conv12_mfma<<<dim3(32, 128, 4), 256, 0, stream>>>(x, w1a, b1, w2bh, b2, f2n, PLANE, 0);
        conv3_mfma<<<dim3(32, 128, 4), 256, 0, stream>>>(f2n, PLANE, 0, w3f, b3, f3all);
    } else {
        for (int b = 0; b < 4; b++) {
            conv12_mfma<<<dim3(32, 128, 1), 256, 0, stream>>>(x, w1a, b1, w2bh, b2, f2n, 0, b);
            conv3_mfma<<<dim3(32, 128, 1), 256, 0, stream>>>(f2n, 0, b, w3f, b3, f3all);
        }
    }
    stdfuse_fused<<<dim3(32, 32, 4), 256, 0, stream>>>(f3all, fw, fb, stats, out);
}